// Round 9
// baseline (414.801 us; speedup 1.0000x reference)
//
#include <hip/hip_runtime.h>

#define HW 1024
#define CCH 256

// ws layout (f32 units):
//   xnT : bf16 [4][1024][256]       off 0            524,288
//   Af16: f16  [4][1024][1024]      off 524,288    2,097,152
//   xc  : f32  [4][1024][1024]      off 2,621,440  4,194,304
//   Wpk : u32  [81][25][16]         off 6,815,744     32,400
//   BT  : f32  [32][3][3][3]        off 6,848,512        864
//   part: f32  [4][8][3][1024]      off 6,849,536     98,304

typedef _Float16 h2v __attribute__((ext_vector_type(2)));
typedef short bf16x8 __attribute__((ext_vector_type(8)));
typedef float f32x4 __attribute__((ext_vector_type(4)));

__device__ __forceinline__ float fdot2(unsigned a, unsigned b, float c) {
#if __has_builtin(__builtin_amdgcn_fdot2)
    return __builtin_amdgcn_fdot2(__builtin_bit_cast(h2v, a),
                                  __builtin_bit_cast(h2v, b), c, false);
#else
    h2v ha = __builtin_bit_cast(h2v, a), hb = __builtin_bit_cast(h2v, b);
    return c + (float)ha.x * (float)hb.x + (float)ha.y * (float)hb.y;
#endif
}
__device__ __forceinline__ unsigned packh2(float x, float y) {
    h2v h;
    h.x = (_Float16)x;
    h.y = (_Float16)y;
    return __builtin_bit_cast(unsigned, h);
}
__device__ __forceinline__ unsigned short f2bf(float f) {
    unsigned u = __float_as_uint(f);
    u += 0x7fffu + ((u >> 16) & 1u);
    return (unsigned short)(u >> 16);
}

// ---- norm: xnT[b][p][c] = bf16( x[b][c][p] / ||x[b][:][p]|| )
__global__ __launch_bounds__(256) void norm_kernel(const float* __restrict__ x,
                                                   unsigned short* __restrict__ xnT) {
    int b = blockIdx.y;
    int p = blockIdx.x * 256 + threadIdx.x;
    const float* xb = x + (size_t)b * CCH * HW;
    float ss = 0.f;
#pragma unroll 8
    for (int c = 0; c < CCH; ++c) { float v = xb[c * HW + p]; ss += v * v; }
    float inv = 1.0f / fmaxf(sqrtf(ss), 1e-12f);
    unsigned* o = (unsigned*)(xnT + ((size_t)b * HW + p) * CCH);
#pragma unroll 4
    for (int c = 0; c < CCH; c += 2) {
        unsigned lo = f2bf(xb[c * HW + p] * inv);
        unsigned hi = f2bf(xb[(c + 1) * HW + p] * inv);
        o[c >> 1] = lo | (hi << 16);
    }
}

// ---- aff (bf16 MFMA): Af16[b][p][m] = f16( g(p,m) * sum_c xnT[p][c]*xnT[m][c] )
__global__ __launch_bounds__(256) void aff_kernel(const unsigned short* __restrict__ xnT,
                                                  unsigned short* __restrict__ Af16) {
    int b = blockIdx.z;
    int p0 = blockIdx.y * 64, m0 = blockIdx.x * 64;
    const unsigned short* X = xnT + (size_t)b * HW * CCH;
    int lane = threadIdx.x & 63, w = threadIdx.x >> 6;
    int pw = p0 + (w >> 1) * 32, mw = m0 + (w & 1) * 32;
    int lr = lane & 15, lg = lane >> 4;
    f32x4 acc[2][2] = {};
    for (int ks = 0; ks < 8; ++ks) {
        int kc = ks * 32 + lg * 8;
        bf16x8 a0 = *(const bf16x8*)&X[(size_t)(pw + lr) * CCH + kc];
        bf16x8 a1 = *(const bf16x8*)&X[(size_t)(pw + 16 + lr) * CCH + kc];
        bf16x8 b0 = *(const bf16x8*)&X[(size_t)(mw + lr) * CCH + kc];
        bf16x8 b1 = *(const bf16x8*)&X[(size_t)(mw + 16 + lr) * CCH + kc];
        acc[0][0] = __builtin_amdgcn_mfma_f32_16x16x32_bf16(a0, b0, acc[0][0], 0, 0, 0);
        acc[0][1] = __builtin_amdgcn_mfma_f32_16x16x32_bf16(a0, b1, acc[0][1], 0, 0, 0);
        acc[1][0] = __builtin_amdgcn_mfma_f32_16x16x32_bf16(a1, b0, acc[1][0], 0, 0, 0);
        acc[1][1] = __builtin_amdgcn_mfma_f32_16x16x32_bf16(a1, b1, acc[1][1], 0, 0, 0);
    }
#pragma unroll
    for (int pi = 0; pi < 2; ++pi)
#pragma unroll
        for (int mi = 0; mi < 2; ++mi)
#pragma unroll
            for (int r = 0; r < 4; ++r) {
                int p = pw + 16 * pi + lg * 4 + r;
                int m = mw + 16 * mi + lr;
                int dr = (m >> 5) - (p >> 5);
                int dc = (m & 31) - (p & 31);
                float gg = 1.0f - __expf(-(float)(dr * dr + dc * dc) * 0.1953125f);
                float v = acc[pi][mi][r] * gg;
                Af16[((size_t)b * HW + p) * HW + m] =
                    __builtin_bit_cast(unsigned short, (_Float16)v);
            }
}

// ---- composed-weight precompute: Wpk[class 81][tp 25][16] f16-pair uints.
__global__ __launch_bounds__(128) void wcomp_kernel(const float* __restrict__ w1,
                                                    const float* __restrict__ w2,
                                                    unsigned* __restrict__ Wpk) {
    int cls = blockIdx.x;
    int t = threadIdx.x;
    if (t < 25) Wpk[cls * 400 + t * 16 + 15] = 0u;  // pad slot: never poison
    if (t >= 125) return;
    int a = t / 25, b_ = (t / 5) % 5, c = t % 5;
    int r1c = cls / 27, c1c = (cls / 9) % 3, r2c = (cls / 3) % 3, c2c = cls % 3;
    float W[5] = {};
#pragma unroll
    for (int d = 0; d < 5; ++d) {
        float s = 0.f;
        for (int i2 = 0; i2 < 3; ++i2) {
            if ((r1c == 0 && i2 == 0) || (r1c == 2 && i2 == 2)) continue;
            int i1 = a - i2;
            if (i1 < 0 || i1 > 2) continue;
            for (int j2 = 0; j2 < 3; ++j2) {
                if ((c1c == 0 && j2 == 0) || (c1c == 2 && j2 == 2)) continue;
                int j1 = b_ - j2;
                if (j1 < 0 || j1 > 2) continue;
                for (int u2 = 0; u2 < 3; ++u2) {
                    if ((r2c == 0 && u2 == 0) || (r2c == 2 && u2 == 2)) continue;
                    int u1 = c - u2;
                    if (u1 < 0 || u1 > 2) continue;
                    for (int v2 = 0; v2 < 3; ++v2) {
                        if ((c2c == 0 && v2 == 0) || (c2c == 2 && v2 == 2)) continue;
                        int v1 = d - v2;
                        if (v1 < 0 || v1 > 2) continue;
                        int o1 = i1 * 27 + j1 * 9 + u1 * 3 + v1;
                        int o2 = i2 * 27 + j2 * 9 + u2 * 3 + v2;
                        for (int ch = 0; ch < 16; ++ch)
                            s += w1[ch * 81 + o1] * w2[ch * 81 + o2];
                    }
                }
            }
        }
        W[d] = s;
    }
    unsigned* o = &Wpk[cls * 400 + (a * 5 + b_) * 16 + c * 3];
    o[0] = packh2(W[0], W[1]);
    o[1] = packh2(W[2], W[3]);
    o[2] = packh2(W[4], 0.f);
}

// ---- bias precompute: BT[r1][c1c][r2c][c2c]
__global__ __launch_bounds__(256) void bt_kernel(const float* __restrict__ w2,
                                                 const float* __restrict__ b1,
                                                 const float* __restrict__ b2,
                                                 float* __restrict__ BT) {
    int i = blockIdx.x * 256 + threadIdx.x;
    if (i >= 864) return;
    int r1 = i / 27, c1c = (i / 9) % 3, r2c = (i / 3) % 3, c2c = i % 3;
    float s = b2[1] + (r1 >= 1 ? b2[0] : 0.f) + (r1 <= 30 ? b2[2] : 0.f);
    for (int i2 = 0; i2 < 3; ++i2) {
        int rr = r1 + i2 - 1;
        if (rr < 0 || rr > 31) continue;
        for (int j2 = 0; j2 < 3; ++j2) {
            if ((c1c == 0 && j2 == 0) || (c1c == 2 && j2 == 2)) continue;
            for (int u2 = 0; u2 < 3; ++u2) {
                if ((r2c == 0 && u2 == 0) || (r2c == 2 && u2 == 2)) continue;
                for (int v2 = 0; v2 < 3; ++v2) {
                    if ((c2c == 0 && v2 == 0) || (c2c == 2 && v2 == 2)) continue;
                    for (int ch = 0; ch < 16; ++ch) {
                        float be = b1[16 + ch] + (rr >= 1 ? b1[ch] : 0.f) +
                                   (rr <= 30 ? b1[32 + ch] : 0.f);
                        s += w2[ch * 81 + i2 * 27 + j2 * 9 + u2 * 3 + v2] * be;
                    }
                }
            }
        }
    }
    BT[i] = s;
}

// ---- main composed conv: CENTER-variant weights (block-uniform, SGPR) for all
// pixels; boundary q-pixels are overwritten exactly by fix_kernel afterwards.
// Halo stride 80 ushorts = 40 dwords == 8 mod 32: lanes (qr,qc)/(qr+4,qc) are the
// only bank aliases -> 2-way across wave64 (free).
#define HS 80
__global__ __launch_bounds__(256) void convc_kernel(const unsigned short* __restrict__ Af16,
                                                    const unsigned* __restrict__ Wpk,
                                                    const float* __restrict__ BT,
                                                    float* __restrict__ xc) {
    __shared__ unsigned short halo[2][36 * HS];
    int tid = threadIdx.x;
    int P = blockIdx.x, b = blockIdx.y;
    int r1 = P >> 5, c1 = P & 31;
    int r1c = (r1 == 0) ? 0 : (r1 == 31) ? 2 : 1;
    int c1c = (c1 == 0) ? 0 : (c1 == 31) ? 2 : 1;

    const uint4* wsrc = (const uint4*)(Wpk + (size_t)((r1c * 3 + c1c) * 9 + 4) * 400);
    float bias = BT[r1 * 27 + c1c * 9 + 4];

    for (int i = tid; i < 36 * HS; i += 256) ((unsigned*)halo)[i] = 0;  // both bufs, dwords

    int qr = tid >> 3, qc = tid & 7;
    int dstw = (qr + 2) * 40 + 2 * qc + 1;  // dword idx within one buffer
    const uint2* Ab = (const uint2*)(Af16 + (size_t)b * HW * HW);

    float acc0 = 0.f, acc1 = 0.f, acc2 = 0.f, acc3 = 0.f;

    int pr0 = min(max(r1 - 2, 0), 31), pc0 = min(max(c1 - 2, 0), 31);
    uint2 pf = Ab[(size_t)(pr0 * 32 + pc0) * 256 + tid];

    __syncthreads();  // zero-init visible
    int buf = 0;

#pragma unroll 1
    for (int tp = 0; tp < 25; ++tp) {
        int tr = tp / 5, tc = tp - tr * 5;
        int apr = r1 + tr - 2, apc = c1 + tc - 2;
        bool valid = ((unsigned)apr < 32u) && ((unsigned)apc < 32u);
        uint2 cur = pf;
        if (tp < 24) {
            int t2 = tp + 1;
            int tr2 = t2 / 5, tc2 = t2 - tr2 * 5;
            int npr = min(max(r1 + tr2 - 2, 0), 31);
            int npc = min(max(c1 + tc2 - 2, 0), 31);
            pf = Ab[(size_t)(npr * 32 + npc) * 256 + tid];
        }
        if (!valid) continue;  // block-uniform skip

        uint4 w4a = wsrc[tp * 4 + 0];  // uniform -> s_load
        uint4 w4b = wsrc[tp * 4 + 1];
        uint4 w4c = wsrc[tp * 4 + 2];
        uint4 w4d = wsrc[tp * 4 + 3];

        unsigned* hb = (unsigned*)halo[buf];
        hb[dstw] = cur.x;
        hb[dstw + 1] = cur.y;
        __syncthreads();

        unsigned wr[16] = {w4a.x, w4a.y, w4a.z, w4a.w, w4b.x, w4b.y, w4b.z, w4b.w,
                           w4c.x, w4c.y, w4c.z, w4c.w, w4d.x, w4d.y, w4d.z, w4d.w};
        const unsigned* hbr = (const unsigned*)halo[buf];
#pragma unroll
        for (int u = 0; u < 5; ++u) {
            const unsigned* dp = hbr + (qr + u) * 40 + 2 * qc;
            uint2 d01 = *(const uint2*)dp;
            uint2 d23 = *(const uint2*)(dp + 2);
            unsigned u4v = dp[4];
            unsigned u0 = d01.x, u1v = d01.y, u2v = d23.x, u3v = d23.y;
            unsigned o0 = (u0 >> 16) | (u1v << 16);
            unsigned o1 = (u1v >> 16) | (u2v << 16);
            unsigned o2 = (u2v >> 16) | (u3v << 16);
            unsigned o3 = (u3v >> 16) | (u4v << 16);
            acc0 = fdot2(wr[u * 3 + 0], u0, acc0);
            acc0 = fdot2(wr[u * 3 + 1], u1v, acc0);
            acc0 = fdot2(wr[u * 3 + 2], u2v, acc0);
            acc1 = fdot2(wr[u * 3 + 0], o0, acc1);
            acc1 = fdot2(wr[u * 3 + 1], o1, acc1);
            acc1 = fdot2(wr[u * 3 + 2], o2, acc1);
            acc2 = fdot2(wr[u * 3 + 0], u1v, acc2);
            acc2 = fdot2(wr[u * 3 + 1], u2v, acc2);
            acc2 = fdot2(wr[u * 3 + 2], u3v, acc2);
            acc3 = fdot2(wr[u * 3 + 0], o1, acc3);
            acc3 = fdot2(wr[u * 3 + 1], o2, acc3);
            acc3 = fdot2(wr[u * 3 + 2], o3, acc3);
        }
        buf ^= 1;
    }

    float4 res = make_float4(acc0 + bias, acc1 + bias, acc2 + bias, acc3 + bias);
    *(float4*)&xc[((size_t)b * HW + P) * HW + qr * 32 + 4 * qc] = res;
}

// ---- boundary fixup: recompute the 124 edge q-pixels per plane exactly.
// Block = plane P; 512 thr = 4 batches x 128. Each thread stages TWO uint2s
// (full 32x32 plane per batch: rows li>>3 and (li>>3)+16).
__global__ __launch_bounds__(512) void fix_kernel(const unsigned short* __restrict__ Af16,
                                                  const unsigned* __restrict__ Wpk,
                                                  const float* __restrict__ BT,
                                                  float* __restrict__ xc) {
    __shared__ __align__(16) unsigned wl[3600];   // 9 variants x 25 x 16
    __shared__ unsigned short hal[4][36 * 40];
    __shared__ float bts[9];
    int tid = threadIdx.x;
    int P = blockIdx.x;
    int r1 = P >> 5, c1 = P & 31;
    int r1c = (r1 == 0) ? 0 : (r1 == 31) ? 2 : 1;
    int c1c = (c1 == 0) ? 0 : (c1 == 31) ? 2 : 1;

    const unsigned* wsrc = Wpk + (size_t)(r1c * 3 + c1c) * 9 * 400;
    for (int i = tid; i < 3600; i += 512) wl[i] = wsrc[i];
    for (int i = tid; i < 2880; i += 512) ((unsigned*)hal)[i] = 0;  // all 4 bufs, dwords
    if (tid < 9) bts[tid] = BT[r1 * 27 + c1c * 9 + tid];

    int bi = tid >> 7, li = tid & 127;
    bool act = li < 124;
    int qr, qc;
    if (li < 32) { qr = 0; qc = li; }
    else if (li < 64) { qr = 31; qc = li - 32; }
    else if (li < 94) { qr = li - 63; qc = 0; }
    else { qr = min(li, 123) - 93; qc = 31; }
    int r2c = (qr == 0) ? 0 : (qr == 31) ? 2 : 1;
    int c2c = (qc == 0) ? 0 : (qc == 31) ? 2 : 1;
    int v = r2c * 3 + c2c;

    const uint2* Ab = (const uint2*)(Af16 + (size_t)bi * HW * HW);
    int dstwA = ((li >> 3) + 2) * 20 + 2 * (li & 7) + 1;   // rows 0..15  -> 2..17
    int dstwB = ((li >> 3) + 18) * 20 + 2 * (li & 7) + 1;  // rows 16..31 -> 18..33

    int pr0 = min(max(r1 - 2, 0), 31), pc0 = min(max(c1 - 2, 0), 31);
    uint2 pfA = Ab[(size_t)(pr0 * 32 + pc0) * 256 + li];
    uint2 pfB = Ab[(size_t)(pr0 * 32 + pc0) * 256 + li + 128];
    float acc = 0.f;

    __syncthreads();

#pragma unroll 1
    for (int tp = 0; tp < 25; ++tp) {
        int tr = tp / 5, tc = tp - tr * 5;
        int apr = r1 + tr - 2, apc = c1 + tc - 2;
        bool valid = ((unsigned)apr < 32u) && ((unsigned)apc < 32u);
        uint2 curA = pfA, curB = pfB;
        if (tp < 24) {
            int t2 = tp + 1;
            int tr2 = t2 / 5, tc2 = t2 - tr2 * 5;
            int npr = min(max(r1 + tr2 - 2, 0), 31);
            int npc = min(max(c1 + tc2 - 2, 0), 31);
            pfA = Ab[(size_t)(npr * 32 + npc) * 256 + li];
            pfB = Ab[(size_t)(npr * 32 + npc) * 256 + li + 128];
        }
        if (!valid) continue;
        __syncthreads();  // prev compute done
        unsigned* hb = (unsigned*)hal[bi];
        hb[dstwA] = curA.x;
        hb[dstwA + 1] = curA.y;
        hb[dstwB] = curB.x;
        hb[dstwB + 1] = curB.y;
        __syncthreads();
        if (act) {
            const uint4* wv4 = (const uint4*)&wl[v * 400 + tp * 16];
            uint4 wa = wv4[0], wb = wv4[1], wc = wv4[2], wd = wv4[3];
            unsigned wr[16] = {wa.x, wa.y, wa.z, wa.w, wb.x, wb.y, wb.z, wb.w,
                               wc.x, wc.y, wc.z, wc.w, wd.x, wd.y, wd.z, wd.w};
#pragma unroll
            for (int c = 0; c < 5; ++c) {
                const unsigned short* hr = &hal[bi][(qr + c) * 40 + qc];
                unsigned a0 = hr[0], a1 = hr[1], a2 = hr[2], a3 = hr[3], a4 = hr[4];
                acc = fdot2(wr[c * 3 + 0], a0 | (a1 << 16), acc);
                acc = fdot2(wr[c * 3 + 1], a2 | (a3 << 16), acc);
                acc = fdot2(wr[c * 3 + 2], a4, acc);
            }
        }
    }

    if (act)
        xc[((size_t)bi * HW + P) * HW + qr * 32 + qc] = acc + bts[v];
}

__device__ __forceinline__ void top3_push(float v, float& t0, float& t1, float& t2) {
    float n0 = fminf(t0, v);
    t0 = fmaxf(t0, v);
    float n1 = fminf(t1, n0);
    t1 = fmaxf(t1, n0);
    t2 = fmaxf(t2, n1);
}

__global__ __launch_bounds__(256) void topk1_kernel(const float* __restrict__ xc,
                                                    float* __restrict__ part) {
    int q = blockIdx.x * 256 + threadIdx.x;
    int pc = blockIdx.y, bi = blockIdx.z;
    float t0 = -1e30f, t1 = -1e30f, t2 = -1e30f;
    const float* xp = xc + (size_t)bi * HW * HW;
    for (int p = pc * 128; p < pc * 128 + 128; ++p)
        top3_push(xp[(size_t)p * HW + q], t0, t1, t2);
    float* pp = part + (size_t)(bi * 8 + pc) * 3 * HW;
    pp[q] = t0;
    pp[HW + q] = t1;
    pp[2 * HW + q] = t2;
}

__global__ __launch_bounds__(256) void topk2_kernel(const float* __restrict__ part,
                                                    float* __restrict__ out) {
    int q = blockIdx.x * 256 + threadIdx.x;
    int bi = blockIdx.y;
    float t0 = -1e30f, t1 = -1e30f, t2 = -1e30f;
    const float* pp = part + (size_t)bi * 24 * HW;
    for (int k = 0; k < 24; ++k) top3_push(pp[(size_t)k * HW + q], t0, t1, t2);
    float* ob = out + (size_t)bi * 3 * HW;
    ob[q] = t0;
    ob[HW + q] = t1;
    ob[2 * HW + q] = t2;
}

extern "C" void kernel_launch(void* const* d_in, const int* in_sizes, int n_in,
                              void* d_out, int out_size, void* d_ws, size_t ws_size,
                              hipStream_t stream) {
    const float* x = (const float*)d_in[0];
    const float* w1 = (const float*)d_in[1];
    const float* b1 = (const float*)d_in[2];
    const float* w2 = (const float*)d_in[3];
    const float* b2 = (const float*)d_in[4];
    float* out = (float*)d_out;
    float* ws = (float*)d_ws;

    unsigned short* xnT = (unsigned short*)ws;
    unsigned short* Af16 = (unsigned short*)(ws + 524288);
    float* xc = ws + 2621440;
    unsigned* Wpk = (unsigned*)(ws + 6815744);
    float* BT = ws + 6848512;
    float* part = ws + 6849536;

    norm_kernel<<<dim3(4, 4), 256, 0, stream>>>(x, xnT);
    aff_kernel<<<dim3(16, 16, 4), 256, 0, stream>>>(xnT, Af16);
    wcomp_kernel<<<81, 128, 0, stream>>>(w1, w2, Wpk);
    bt_kernel<<<4, 256, 0, stream>>>(w2, b1, b2, BT);
    convc_kernel<<<dim3(1024, 4), 256, 0, stream>>>(Af16, Wpk, BT, xc);
    fix_kernel<<<1024, 512, 0, stream>>>(Af16, Wpk, BT, xc);
    topk1_kernel<<<dim3(4, 8, 4), 256, 0, stream>>>(xc, part);
    topk2_kernel<<<dim3(4, 4), 256, 0, stream>>>(part, out);
}

// Round 10
// 318.533 us; speedup vs baseline: 1.3022x; 1.3022x over previous
//
#include <hip/hip_runtime.h>

#define HW 1024
#define CCH 256

// ws layout (f32 units):
//   xnT : bf16 [4][1024][256]       off 0            524,288
//   Af16: f16  [4][1024][1024]      off 524,288    2,097,152
//   xc  : f32  [4][1024][1024]      off 2,621,440  4,194,304
//   Wpk : u32  [81][25][16]         off 6,815,744     32,400
//   BT  : f32  [32][3][3][3]        off 6,848,512        864
//   part: f32  [4][32][3][1024]     off 6,849,536    393,216
//   Apad: f16  [4][1024][36][40]    off 7,242,752  2,949,120
// end 10,191,872 (< 23M proven capacity)

typedef _Float16 h2v __attribute__((ext_vector_type(2)));
typedef short bf16x8 __attribute__((ext_vector_type(8)));
typedef float f32x4 __attribute__((ext_vector_type(4)));

__device__ __forceinline__ float fdot2(unsigned a, unsigned b, float c) {
#if __has_builtin(__builtin_amdgcn_fdot2)
    return __builtin_amdgcn_fdot2(__builtin_bit_cast(h2v, a),
                                  __builtin_bit_cast(h2v, b), c, false);
#else
    h2v ha = __builtin_bit_cast(h2v, a), hb = __builtin_bit_cast(h2v, b);
    return c + (float)ha.x * (float)hb.x + (float)ha.y * (float)hb.y;
#endif
}
__device__ __forceinline__ unsigned packh2(float x, float y) {
    h2v h;
    h.x = (_Float16)x;
    h.y = (_Float16)y;
    return __builtin_bit_cast(unsigned, h);
}
__device__ __forceinline__ unsigned short f2bf(float f) {
    unsigned u = __float_as_uint(f);
    u += 0x7fffu + ((u >> 16) & 1u);
    return (unsigned short)(u >> 16);
}

// ---- norm: block = 16 p-pixels, 256 thr = 16 c-groups x 16 p. Coalesced both ways.
__global__ __launch_bounds__(256) void norm_kernel(const float* __restrict__ x,
                                                   unsigned short* __restrict__ xnT) {
    __shared__ float red[16][17];
    __shared__ float invs[16];
    int b = blockIdx.y;
    int p0 = blockIdx.x * 16;
    int cg = threadIdx.x >> 4;
    int pp = threadIdx.x & 15;
    int p = p0 + pp;
    const float* xb = x + (size_t)b * CCH * HW;
    float ss = 0.f;
#pragma unroll
    for (int i = 0; i < 16; ++i) {
        float v = xb[(size_t)(cg * 16 + i) * HW + p];
        ss += v * v;
    }
    red[cg][pp] = ss;
    __syncthreads();
    if (threadIdx.x < 16) {
        float s = 0.f;
#pragma unroll
        for (int g = 0; g < 16; ++g) s += red[g][threadIdx.x];
        invs[threadIdx.x] = 1.0f / fmaxf(sqrtf(s), 1e-12f);
    }
    __syncthreads();
    float inv = invs[pp];
    unsigned* o = (unsigned*)(xnT + ((size_t)b * HW + p) * CCH) + cg * 8;
#pragma unroll
    for (int i = 0; i < 8; ++i) {
        int c = cg * 16 + 2 * i;
        unsigned lo = f2bf(xb[(size_t)c * HW + p] * inv);
        unsigned hi = f2bf(xb[(size_t)(c + 1) * HW + p] * inv);
        o[i] = lo | (hi << 16);
    }
}

// ---- aff (bf16 MFMA): Af16[b][p][m] = f16( g(p,m) * sum_c xnT[p][c]*xnT[m][c] )
__global__ __launch_bounds__(256) void aff_kernel(const unsigned short* __restrict__ xnT,
                                                  unsigned short* __restrict__ Af16) {
    int b = blockIdx.z;
    int p0 = blockIdx.y * 64, m0 = blockIdx.x * 64;
    const unsigned short* X = xnT + (size_t)b * HW * CCH;
    int lane = threadIdx.x & 63, w = threadIdx.x >> 6;
    int pw = p0 + (w >> 1) * 32, mw = m0 + (w & 1) * 32;
    int lr = lane & 15, lg = lane >> 4;
    f32x4 acc[2][2] = {};
    for (int ks = 0; ks < 8; ++ks) {
        int kc = ks * 32 + lg * 8;
        bf16x8 a0 = *(const bf16x8*)&X[(size_t)(pw + lr) * CCH + kc];
        bf16x8 a1 = *(const bf16x8*)&X[(size_t)(pw + 16 + lr) * CCH + kc];
        bf16x8 b0 = *(const bf16x8*)&X[(size_t)(mw + lr) * CCH + kc];
        bf16x8 b1 = *(const bf16x8*)&X[(size_t)(mw + 16 + lr) * CCH + kc];
        acc[0][0] = __builtin_amdgcn_mfma_f32_16x16x32_bf16(a0, b0, acc[0][0], 0, 0, 0);
        acc[0][1] = __builtin_amdgcn_mfma_f32_16x16x32_bf16(a0, b1, acc[0][1], 0, 0, 0);
        acc[1][0] = __builtin_amdgcn_mfma_f32_16x16x32_bf16(a1, b0, acc[1][0], 0, 0, 0);
        acc[1][1] = __builtin_amdgcn_mfma_f32_16x16x32_bf16(a1, b1, acc[1][1], 0, 0, 0);
    }
#pragma unroll
    for (int pi = 0; pi < 2; ++pi)
#pragma unroll
        for (int mi = 0; mi < 2; ++mi)
#pragma unroll
            for (int r = 0; r < 4; ++r) {
                int p = pw + 16 * pi + lg * 4 + r;
                int m = mw + 16 * mi + lr;
                int dr = (m >> 5) - (p >> 5);
                int dc = (m & 31) - (p & 31);
                float gg = 1.0f - __expf(-(float)(dr * dr + dc * dc) * 0.1953125f);
                float v = acc[pi][mi][r] * gg;
                Af16[((size_t)b * HW + p) * HW + m] =
                    __builtin_bit_cast(unsigned short, (_Float16)v);
            }
}

// ---- composed-weight precompute: Wpk[class 81][tp 25][16] f16-pair uints.
__global__ __launch_bounds__(128) void wcomp_kernel(const float* __restrict__ w1,
                                                    const float* __restrict__ w2,
                                                    unsigned* __restrict__ Wpk) {
    int cls = blockIdx.x;
    int t = threadIdx.x;
    if (t < 25) Wpk[cls * 400 + t * 16 + 15] = 0u;
    if (t >= 125) return;
    int a = t / 25, b_ = (t / 5) % 5, c = t % 5;
    int r1c = cls / 27, c1c = (cls / 9) % 3, r2c = (cls / 3) % 3, c2c = cls % 3;
    float W[5] = {};
#pragma unroll
    for (int d = 0; d < 5; ++d) {
        float s = 0.f;
        for (int i2 = 0; i2 < 3; ++i2) {
            if ((r1c == 0 && i2 == 0) || (r1c == 2 && i2 == 2)) continue;
            int i1 = a - i2;
            if (i1 < 0 || i1 > 2) continue;
            for (int j2 = 0; j2 < 3; ++j2) {
                if ((c1c == 0 && j2 == 0) || (c1c == 2 && j2 == 2)) continue;
                int j1 = b_ - j2;
                if (j1 < 0 || j1 > 2) continue;
                for (int u2 = 0; u2 < 3; ++u2) {
                    if ((r2c == 0 && u2 == 0) || (r2c == 2 && u2 == 2)) continue;
                    int u1 = c - u2;
                    if (u1 < 0 || u1 > 2) continue;
                    for (int v2 = 0; v2 < 3; ++v2) {
                        if ((c2c == 0 && v2 == 0) || (c2c == 2 && v2 == 2)) continue;
                        int v1 = d - v2;
                        if (v1 < 0 || v1 > 2) continue;
                        int o1 = i1 * 27 + j1 * 9 + u1 * 3 + v1;
                        int o2 = i2 * 27 + j2 * 9 + u2 * 3 + v2;
                        for (int ch = 0; ch < 16; ++ch)
                            s += w1[ch * 81 + o1] * w2[ch * 81 + o2];
                    }
                }
            }
        }
        W[d] = s;
    }
    unsigned* o = &Wpk[cls * 400 + (a * 5 + b_) * 16 + c * 3];
    o[0] = packh2(W[0], W[1]);
    o[1] = packh2(W[2], W[3]);
    o[2] = packh2(W[4], 0.f);
}

// ---- bias precompute: BT[r1][c1c][r2c][c2c]
__global__ __launch_bounds__(256) void bt_kernel(const float* __restrict__ w2,
                                                 const float* __restrict__ b1,
                                                 const float* __restrict__ b2,
                                                 float* __restrict__ BT) {
    int i = blockIdx.x * 256 + threadIdx.x;
    if (i >= 864) return;
    int r1 = i / 27, c1c = (i / 9) % 3, r2c = (i / 3) % 3, c2c = i % 3;
    float s = b2[1] + (r1 >= 1 ? b2[0] : 0.f) + (r1 <= 30 ? b2[2] : 0.f);
    for (int i2 = 0; i2 < 3; ++i2) {
        int rr = r1 + i2 - 1;
        if (rr < 0 || rr > 31) continue;
        for (int j2 = 0; j2 < 3; ++j2) {
            if ((c1c == 0 && j2 == 0) || (c1c == 2 && j2 == 2)) continue;
            for (int u2 = 0; u2 < 3; ++u2) {
                if ((r2c == 0 && u2 == 0) || (r2c == 2 && u2 == 2)) continue;
                for (int v2 = 0; v2 < 3; ++v2) {
                    if ((c2c == 0 && v2 == 0) || (c2c == 2 && v2 == 2)) continue;
                    for (int ch = 0; ch < 16; ++ch) {
                        float be = b1[16 + ch] + (rr >= 1 ? b1[ch] : 0.f) +
                                   (rr <= 30 ? b1[32 + ch] : 0.f);
                        s += w2[ch * 81 + i2 * 27 + j2 * 9 + u2 * 3 + v2] * be;
                    }
                }
            }
        }
    }
    BT[i] = s;
}

// ---- main composed conv (center-variant, SGPR weights) — unchanged from r9.
#define HS 80
__global__ __launch_bounds__(256) void convc_kernel(const unsigned short* __restrict__ Af16,
                                                    const unsigned* __restrict__ Wpk,
                                                    const float* __restrict__ BT,
                                                    float* __restrict__ xc) {
    __shared__ unsigned short halo[2][36 * HS];
    int tid = threadIdx.x;
    int P = blockIdx.x, b = blockIdx.y;
    int r1 = P >> 5, c1 = P & 31;
    int r1c = (r1 == 0) ? 0 : (r1 == 31) ? 2 : 1;
    int c1c = (c1 == 0) ? 0 : (c1 == 31) ? 2 : 1;

    const uint4* wsrc = (const uint4*)(Wpk + (size_t)((r1c * 3 + c1c) * 9 + 4) * 400);
    float bias = BT[r1 * 27 + c1c * 9 + 4];

    for (int i = tid; i < 36 * HS; i += 256) ((unsigned*)halo)[i] = 0;

    int qr = tid >> 3, qc = tid & 7;
    int dstw = (qr + 2) * 40 + 2 * qc + 1;
    const uint2* Ab = (const uint2*)(Af16 + (size_t)b * HW * HW);

    float acc0 = 0.f, acc1 = 0.f, acc2 = 0.f, acc3 = 0.f;

    int pr0 = min(max(r1 - 2, 0), 31), pc0 = min(max(c1 - 2, 0), 31);
    uint2 pf = Ab[(size_t)(pr0 * 32 + pc0) * 256 + tid];

    __syncthreads();
    int buf = 0;

#pragma unroll 1
    for (int tp = 0; tp < 25; ++tp) {
        int tr = tp / 5, tc = tp - tr * 5;
        int apr = r1 + tr - 2, apc = c1 + tc - 2;
        bool valid = ((unsigned)apr < 32u) && ((unsigned)apc < 32u);
        uint2 cur = pf;
        if (tp < 24) {
            int t2 = tp + 1;
            int tr2 = t2 / 5, tc2 = t2 - tr2 * 5;
            int npr = min(max(r1 + tr2 - 2, 0), 31);
            int npc = min(max(c1 + tc2 - 2, 0), 31);
            pf = Ab[(size_t)(npr * 32 + npc) * 256 + tid];
        }
        if (!valid) continue;

        uint4 w4a = wsrc[tp * 4 + 0];
        uint4 w4b = wsrc[tp * 4 + 1];
        uint4 w4c = wsrc[tp * 4 + 2];
        uint4 w4d = wsrc[tp * 4 + 3];

        unsigned* hb = (unsigned*)halo[buf];
        hb[dstw] = cur.x;
        hb[dstw + 1] = cur.y;
        __syncthreads();

        unsigned wr[16] = {w4a.x, w4a.y, w4a.z, w4a.w, w4b.x, w4b.y, w4b.z, w4b.w,
                           w4c.x, w4c.y, w4c.z, w4c.w, w4d.x, w4d.y, w4d.z, w4d.w};
        const unsigned* hbr = (const unsigned*)halo[buf];
#pragma unroll
        for (int u = 0; u < 5; ++u) {
            const unsigned* dp = hbr + (qr + u) * 40 + 2 * qc;
            uint2 d01 = *(const uint2*)dp;
            uint2 d23 = *(const uint2*)(dp + 2);
            unsigned u4v = dp[4];
            unsigned u0 = d01.x, u1v = d01.y, u2v = d23.x, u3v = d23.y;
            unsigned o0 = (u0 >> 16) | (u1v << 16);
            unsigned o1 = (u1v >> 16) | (u2v << 16);
            unsigned o2 = (u2v >> 16) | (u3v << 16);
            unsigned o3 = (u3v >> 16) | (u4v << 16);
            acc0 = fdot2(wr[u * 3 + 0], u0, acc0);
            acc0 = fdot2(wr[u * 3 + 1], u1v, acc0);
            acc0 = fdot2(wr[u * 3 + 2], u2v, acc0);
            acc1 = fdot2(wr[u * 3 + 0], o0, acc1);
            acc1 = fdot2(wr[u * 3 + 1], o1, acc1);
            acc1 = fdot2(wr[u * 3 + 2], o2, acc1);
            acc2 = fdot2(wr[u * 3 + 0], u1v, acc2);
            acc2 = fdot2(wr[u * 3 + 1], u2v, acc2);
            acc2 = fdot2(wr[u * 3 + 2], u3v, acc2);
            acc3 = fdot2(wr[u * 3 + 0], o1, acc3);
            acc3 = fdot2(wr[u * 3 + 1], o2, acc3);
            acc3 = fdot2(wr[u * 3 + 2], o3, acc3);
        }
        buf ^= 1;
    }

    float4 res = make_float4(acc0 + bias, acc1 + bias, acc2 + bias, acc3 + bias);
    *(float4*)&xc[((size_t)b * HW + P) * HW + qr * 32 + 4 * qc] = res;
}

// ---- expand: zero-padded copy Apad[b][plane][36][40] (f16), dword-granular.
__global__ __launch_bounds__(256) void expand_kernel(const unsigned short* __restrict__ Af16,
                                                     unsigned* __restrict__ Apad32) {
    int plane = blockIdx.x, b = blockIdx.y;
    const unsigned* src = (const unsigned*)(Af16 + ((size_t)b * HW + plane) * HW);
    unsigned* dst = Apad32 + ((size_t)b * HW + plane) * 720;
    for (int k = threadIdx.x; k < 720; k += 256) {
        int pr = k / 20, pcd = k - pr * 20;
        unsigned val = 0;
        if (pr >= 2 && pr < 34 && pcd >= 1 && pcd <= 16)
            val = src[(pr - 2) * 16 + (pcd - 1)];
        dst[k] = val;
    }
}

// ---- boundary fixup, barrier-free: direct padded-global reads, 1 plane/block.
__global__ __launch_bounds__(128) void fix_kernel(const unsigned* __restrict__ Apad32,
                                                  const unsigned* __restrict__ Wpk,
                                                  const float* __restrict__ BT,
                                                  float* __restrict__ xc) {
    __shared__ __align__(16) unsigned wl[3600];
    __shared__ float bts[9];
    int tid = threadIdx.x;
    int P = blockIdx.x, b = blockIdx.y;
    int r1 = P >> 5, c1 = P & 31;
    int r1c = (r1 == 0) ? 0 : (r1 == 31) ? 2 : 1;
    int c1c = (c1 == 0) ? 0 : (c1 == 31) ? 2 : 1;

    const unsigned* wsrc = Wpk + (size_t)(r1c * 3 + c1c) * 3600;
    for (int i = tid; i < 3600; i += 128) wl[i] = wsrc[i];
    if (tid < 9) bts[tid] = BT[r1 * 27 + c1c * 9 + tid];

    int li = tid;
    bool act = li < 124;
    int qr, qc;
    if (li < 32) { qr = 0; qc = li; }
    else if (li < 64) { qr = 31; qc = li - 32; }
    else if (li < 94) { qr = li - 63; qc = 0; }
    else { qr = min(li, 123) - 93; qc = 31; }
    int r2c = (qr == 0) ? 0 : (qr == 31) ? 2 : 1;
    int c2c = (qc == 0) ? 0 : (qc == 31) ? 2 : 1;
    int v = r2c * 3 + c2c;
    int sh = (qc & 1) * 16;
    int sd = qc >> 1;

    __syncthreads();
    float acc = 0.f;

#pragma unroll 1
    for (int tp = 0; tp < 25; ++tp) {
        int tr = tp / 5, tc = tp - tr * 5;
        int apr = r1 + tr - 2, apc = c1 + tc - 2;
        if ((unsigned)apr >= 32u || (unsigned)apc >= 32u) continue;  // uniform
        const unsigned* tpl = Apad32 + ((size_t)b * HW + apr * 32 + apc) * 720;
        const uint4* wv4 = (const uint4*)&wl[v * 400 + tp * 16];
        uint4 wa = wv4[0], wb = wv4[1], wc2 = wv4[2], wd = wv4[3];
        unsigned wr[16] = {wa.x, wa.y, wa.z, wa.w, wb.x, wb.y, wb.z, wb.w,
                           wc2.x, wc2.y, wc2.z, wc2.w, wd.x, wd.y, wd.z, wd.w};
#pragma unroll
        for (int u = 0; u < 5; ++u) {
            const unsigned* rp = tpl + (qr + u) * 20 + sd;
            unsigned d0 = rp[0], d1 = rp[1], d2 = rp[2];
            unsigned pa = __builtin_amdgcn_alignbit(d1, d0, sh);
            unsigned pb = __builtin_amdgcn_alignbit(d2, d1, sh);
            unsigned pc_ = __builtin_amdgcn_alignbit(0u, d2, sh);
            acc = fdot2(wr[u * 3 + 0], pa, acc);
            acc = fdot2(wr[u * 3 + 1], pb, acc);
            acc = fdot2(wr[u * 3 + 2], pc_, acc);
        }
    }

    if (act)
        xc[((size_t)b * HW + P) * HW + qr * 32 + qc] = acc + bts[v];
}

__device__ __forceinline__ void top3_push(float v, float& t0, float& t1, float& t2) {
    float n0 = fminf(t0, v);
    t0 = fmaxf(t0, v);
    float n1 = fminf(t1, n0);
    t1 = fmaxf(t1, n0);
    t2 = fmaxf(t2, n1);
}

__global__ __launch_bounds__(256) void topk1_kernel(const float* __restrict__ xc,
                                                    float* __restrict__ part) {
    int q = blockIdx.x * 256 + threadIdx.x;
    int pc = blockIdx.y, bi = blockIdx.z;
    float t0 = -1e30f, t1 = -1e30f, t2 = -1e30f;
    const float* xp = xc + (size_t)bi * HW * HW;
    for (int p = pc * 32; p < pc * 32 + 32; ++p)
        top3_push(xp[(size_t)p * HW + q], t0, t1, t2);
    float* pp = part + (size_t)(bi * 32 + pc) * 3 * HW;
    pp[q] = t0;
    pp[HW + q] = t1;
    pp[2 * HW + q] = t2;
}

__global__ __launch_bounds__(256) void topk2_kernel(const float* __restrict__ part,
                                                    float* __restrict__ out) {
    int q = blockIdx.x * 256 + threadIdx.x;
    int bi = blockIdx.y;
    float t0 = -1e30f, t1 = -1e30f, t2 = -1e30f;
    const float* pp = part + (size_t)bi * 96 * HW;
    for (int k = 0; k < 96; ++k) top3_push(pp[(size_t)k * HW + q], t0, t1, t2);
    float* ob = out + (size_t)bi * 3 * HW;
    ob[q] = t0;
    ob[HW + q] = t1;
    ob[2 * HW + q] = t2;
}

extern "C" void kernel_launch(void* const* d_in, const int* in_sizes, int n_in,
                              void* d_out, int out_size, void* d_ws, size_t ws_size,
                              hipStream_t stream) {
    const float* x = (const float*)d_in[0];
    const float* w1 = (const float*)d_in[1];
    const float* b1 = (const float*)d_in[2];
    const float* w2 = (const float*)d_in[3];
    const float* b2 = (const float*)d_in[4];
    float* out = (float*)d_out;
    float* ws = (float*)d_ws;

    unsigned short* xnT = (unsigned short*)ws;
    unsigned short* Af16 = (unsigned short*)(ws + 524288);
    float* xc = ws + 2621440;
    unsigned* Wpk = (unsigned*)(ws + 6815744);
    float* BT = ws + 6848512;
    float* part = ws + 6849536;
    unsigned* Apad32 = (unsigned*)(ws + 7242752);

    norm_kernel<<<dim3(64, 4), 256, 0, stream>>>(x, xnT);
    aff_kernel<<<dim3(16, 16, 4), 256, 0, stream>>>(xnT, Af16);
    expand_kernel<<<dim3(1024, 4), 256, 0, stream>>>(Af16, Apad32);
    wcomp_kernel<<<81, 128, 0, stream>>>(w1, w2, Wpk);
    bt_kernel<<<4, 256, 0, stream>>>(w2, b1, b2, BT);
    convc_kernel<<<dim3(1024, 4), 256, 0, stream>>>(Af16, Wpk, BT, xc);
    fix_kernel<<<dim3(1024, 4), 128, 0, stream>>>(Apad32, Wpk, BT, xc);
    topk1_kernel<<<dim3(4, 32, 4), 256, 0, stream>>>(xc, part);
    topk2_kernel<<<dim3(4, 4), 256, 0, stream>>>(part, out);
}

// Round 11
// 184.795 us; speedup vs baseline: 2.2447x; 1.7237x over previous
//
#include <hip/hip_runtime.h>

#define HW 1024
#define CCH 256

// ws layout (f32 units):
//   xnT : bf16 [4][1024][256]       off 0            524,288
//   Af16: f16  [4][1024][1024]      off 524,288    2,097,152
//   xc  : f32  [4][1024][1024]      off 2,621,440  4,194,304
//   Wpk : u32  [81][25][16]         off 6,815,744     32,400
//   BT  : f32  [32][3][3][3]        off 6,848,512        864
//   part: f32  [4][32][3][1024]     off 6,849,536    393,216
//   Apad: f16  [4][1024][36][40]    off 7,242,752  2,949,120
//   G   : f32  [81][81]             off 10,191,872      6,561

typedef _Float16 h2v __attribute__((ext_vector_type(2)));
typedef short bf16x8 __attribute__((ext_vector_type(8)));
typedef float f32x4 __attribute__((ext_vector_type(4)));

__device__ __forceinline__ float fdot2(unsigned a, unsigned b, float c) {
#if __has_builtin(__builtin_amdgcn_fdot2)
    return __builtin_amdgcn_fdot2(__builtin_bit_cast(h2v, a),
                                  __builtin_bit_cast(h2v, b), c, false);
#else
    h2v ha = __builtin_bit_cast(h2v, a), hb = __builtin_bit_cast(h2v, b);
    return c + (float)ha.x * (float)hb.x + (float)ha.y * (float)hb.y;
#endif
}
__device__ __forceinline__ unsigned packh2(float x, float y) {
    h2v h;
    h.x = (_Float16)x;
    h.y = (_Float16)y;
    return __builtin_bit_cast(unsigned, h);
}
__device__ __forceinline__ unsigned short f2bf(float f) {
    unsigned u = __float_as_uint(f);
    u += 0x7fffu + ((u >> 16) & 1u);
    return (unsigned short)(u >> 16);
}

// ---- norm: block = 16 p-pixels, 256 thr = 16 c-groups x 16 p.
__global__ __launch_bounds__(256) void norm_kernel(const float* __restrict__ x,
                                                   unsigned short* __restrict__ xnT) {
    __shared__ float red[16][17];
    __shared__ float invs[16];
    int b = blockIdx.y;
    int p0 = blockIdx.x * 16;
    int cg = threadIdx.x >> 4;
    int pp = threadIdx.x & 15;
    int p = p0 + pp;
    const float* xb = x + (size_t)b * CCH * HW;
    float ss = 0.f;
#pragma unroll
    for (int i = 0; i < 16; ++i) {
        float v = xb[(size_t)(cg * 16 + i) * HW + p];
        ss += v * v;
    }
    red[cg][pp] = ss;
    __syncthreads();
    if (threadIdx.x < 16) {
        float s = 0.f;
#pragma unroll
        for (int g = 0; g < 16; ++g) s += red[g][threadIdx.x];
        invs[threadIdx.x] = 1.0f / fmaxf(sqrtf(s), 1e-12f);
    }
    __syncthreads();
    float inv = invs[pp];
    unsigned* o = (unsigned*)(xnT + ((size_t)b * HW + p) * CCH) + cg * 8;
#pragma unroll
    for (int i = 0; i < 8; ++i) {
        int c = cg * 16 + 2 * i;
        unsigned lo = f2bf(xb[(size_t)c * HW + p] * inv);
        unsigned hi = f2bf(xb[(size_t)(c + 1) * HW + p] * inv);
        o[i] = lo | (hi << 16);
    }
}

// ---- aff (bf16 MFMA)
__global__ __launch_bounds__(256) void aff_kernel(const unsigned short* __restrict__ xnT,
                                                  unsigned short* __restrict__ Af16) {
    int b = blockIdx.z;
    int p0 = blockIdx.y * 64, m0 = blockIdx.x * 64;
    const unsigned short* X = xnT + (size_t)b * HW * CCH;
    int lane = threadIdx.x & 63, w = threadIdx.x >> 6;
    int pw = p0 + (w >> 1) * 32, mw = m0 + (w & 1) * 32;
    int lr = lane & 15, lg = lane >> 4;
    f32x4 acc[2][2] = {};
    for (int ks = 0; ks < 8; ++ks) {
        int kc = ks * 32 + lg * 8;
        bf16x8 a0 = *(const bf16x8*)&X[(size_t)(pw + lr) * CCH + kc];
        bf16x8 a1 = *(const bf16x8*)&X[(size_t)(pw + 16 + lr) * CCH + kc];
        bf16x8 b0 = *(const bf16x8*)&X[(size_t)(mw + lr) * CCH + kc];
        bf16x8 b1 = *(const bf16x8*)&X[(size_t)(mw + 16 + lr) * CCH + kc];
        acc[0][0] = __builtin_amdgcn_mfma_f32_16x16x32_bf16(a0, b0, acc[0][0], 0, 0, 0);
        acc[0][1] = __builtin_amdgcn_mfma_f32_16x16x32_bf16(a0, b1, acc[0][1], 0, 0, 0);
        acc[1][0] = __builtin_amdgcn_mfma_f32_16x16x32_bf16(a1, b0, acc[1][0], 0, 0, 0);
        acc[1][1] = __builtin_amdgcn_mfma_f32_16x16x32_bf16(a1, b1, acc[1][1], 0, 0, 0);
    }
#pragma unroll
    for (int pi = 0; pi < 2; ++pi)
#pragma unroll
        for (int mi = 0; mi < 2; ++mi)
#pragma unroll
            for (int r = 0; r < 4; ++r) {
                int p = pw + 16 * pi + lg * 4 + r;
                int m = mw + 16 * mi + lr;
                int dr = (m >> 5) - (p >> 5);
                int dc = (m & 31) - (p & 31);
                float gg = 1.0f - __expf(-(float)(dr * dr + dc * dc) * 0.1953125f);
                float v = acc[pi][mi][r] * gg;
                Af16[((size_t)b * HW + p) * HW + m] =
                    __builtin_bit_cast(unsigned short, (_Float16)v);
            }
}

// ---- G[o1][o2] = sum_ch w1[ch][o1]*w2[ch][o2]  (w1,w2 LDS-staged)
__global__ __launch_bounds__(256) void g_kernel(const float* __restrict__ w1,
                                                const float* __restrict__ w2,
                                                float* __restrict__ G) {
    __shared__ float w1s[1296], w2s[1296];
    int tid = threadIdx.x;
    for (int i = tid; i < 1296; i += 256) { w1s[i] = w1[i]; w2s[i] = w2[i]; }
    __syncthreads();
    int idx = blockIdx.x * 256 + tid;
    if (idx < 6561) {
        int o1 = idx / 81, o2 = idx - o1 * 81;
        float s = 0.f;
#pragma unroll
        for (int ch = 0; ch < 16; ++ch) s += w1s[ch * 81 + o1] * w2s[ch * 81 + o2];
        G[idx] = s;
    }
}

// ---- wcomp from G (LDS-staged): Wpk[class 81][tp 25][16] f16-pair uints.
__global__ __launch_bounds__(128) void wcomp_kernel(const float* __restrict__ G,
                                                    unsigned* __restrict__ Wpk) {
    __shared__ float Gs[6561];
    int cls = blockIdx.x;
    int t = threadIdx.x;
    for (int i = t; i < 6561; i += 128) Gs[i] = G[i];
    if (t < 25) Wpk[cls * 400 + t * 16 + 15] = 0u;
    __syncthreads();
    if (t >= 125) return;
    int a = t / 25, b_ = (t / 5) % 5, c = t % 5;
    int r1c = cls / 27, c1c = (cls / 9) % 3, r2c = (cls / 3) % 3, c2c = cls % 3;
    float W[5] = {};
    for (int i2 = 0; i2 < 3; ++i2) {
        if ((r1c == 0 && i2 == 0) || (r1c == 2 && i2 == 2)) continue;
        int i1 = a - i2;
        if (i1 < 0 || i1 > 2) continue;
        for (int j2 = 0; j2 < 3; ++j2) {
            if ((c1c == 0 && j2 == 0) || (c1c == 2 && j2 == 2)) continue;
            int j1 = b_ - j2;
            if (j1 < 0 || j1 > 2) continue;
            for (int u2 = 0; u2 < 3; ++u2) {
                if ((r2c == 0 && u2 == 0) || (r2c == 2 && u2 == 2)) continue;
                int u1 = c - u2;
                if (u1 < 0 || u1 > 2) continue;
                for (int v2 = 0; v2 < 3; ++v2) {
                    if ((c2c == 0 && v2 == 0) || (c2c == 2 && v2 == 2)) continue;
                    int o2 = i2 * 27 + j2 * 9 + u2 * 3 + v2;
                    int o1b = i1 * 27 + j1 * 9 + u1 * 3;
#pragma unroll
                    for (int d = 0; d < 5; ++d) {
                        int v1 = d - v2;
                        if (v1 < 0 || v1 > 2) continue;
                        W[d] += Gs[(o1b + v1) * 81 + o2];
                    }
                }
            }
        }
    }
    unsigned* o = &Wpk[cls * 400 + (a * 5 + b_) * 16 + c * 3];
    o[0] = packh2(W[0], W[1]);
    o[1] = packh2(W[2], W[3]);
    o[2] = packh2(W[4], 0.f);
}

// ---- bt via S-tables, single block.
__global__ __launch_bounds__(1024) void bt_kernel(const float* __restrict__ w2,
                                                  const float* __restrict__ b1,
                                                  const float* __restrict__ b2,
                                                  float* __restrict__ BT) {
    __shared__ float w2s[1296], b1s[48], S0[81], S1[81], S2[81];
    int t = threadIdx.x;
    for (int i = t; i < 1296; i += 1024) w2s[i] = w2[i];
    if (t < 48) b1s[t] = b1[t];
    __syncthreads();
    if (t < 81) {
        float s0 = 0.f, s1 = 0.f, s2 = 0.f;
#pragma unroll
        for (int ch = 0; ch < 16; ++ch) {
            float w = w2s[ch * 81 + t];
            s0 += w * b1s[16 + ch];
            s1 += w * b1s[ch];
            s2 += w * b1s[32 + ch];
        }
        S0[t] = s0; S1[t] = s1; S2[t] = s2;
    }
    __syncthreads();
    if (t >= 864) return;
    int r1 = t / 27, c1c = (t / 9) % 3, r2c = (t / 3) % 3, c2c = t % 3;
    float s = b2[1] + (r1 >= 1 ? b2[0] : 0.f) + (r1 <= 30 ? b2[2] : 0.f);
    for (int i2 = 0; i2 < 3; ++i2) {
        int rr = r1 + i2 - 1;
        if (rr < 0 || rr > 31) continue;
        float m1 = (rr >= 1) ? 1.f : 0.f, m2 = (rr <= 30) ? 1.f : 0.f;
        for (int j2 = 0; j2 < 3; ++j2) {
            if ((c1c == 0 && j2 == 0) || (c1c == 2 && j2 == 2)) continue;
            for (int u2 = 0; u2 < 3; ++u2) {
                if ((r2c == 0 && u2 == 0) || (r2c == 2 && u2 == 2)) continue;
                for (int v2 = 0; v2 < 3; ++v2) {
                    if ((c2c == 0 && v2 == 0) || (c2c == 2 && v2 == 2)) continue;
                    int o2 = i2 * 27 + j2 * 9 + u2 * 3 + v2;
                    s += S0[o2] + m1 * S1[o2] + m2 * S2[o2];
                }
            }
        }
    }
    BT[t] = s;
}

// ---- main composed conv (center-variant, SGPR weights)
#define HS 80
__global__ __launch_bounds__(256) void convc_kernel(const unsigned short* __restrict__ Af16,
                                                    const unsigned* __restrict__ Wpk,
                                                    const float* __restrict__ BT,
                                                    float* __restrict__ xc) {
    __shared__ unsigned short halo[2][36 * HS];
    int tid = threadIdx.x;
    int P = blockIdx.x, b = blockIdx.y;
    int r1 = P >> 5, c1 = P & 31;
    int r1c = (r1 == 0) ? 0 : (r1 == 31) ? 2 : 1;
    int c1c = (c1 == 0) ? 0 : (c1 == 31) ? 2 : 1;

    const uint4* wsrc = (const uint4*)(Wpk + (size_t)((r1c * 3 + c1c) * 9 + 4) * 400);
    float bias = BT[r1 * 27 + c1c * 9 + 4];

    for (int i = tid; i < 36 * HS; i += 256) ((unsigned*)halo)[i] = 0;

    int qr = tid >> 3, qc = tid & 7;
    int dstw = (qr + 2) * 40 + 2 * qc + 1;
    const uint2* Ab = (const uint2*)(Af16 + (size_t)b * HW * HW);

    float acc0 = 0.f, acc1 = 0.f, acc2 = 0.f, acc3 = 0.f;

    int pr0 = min(max(r1 - 2, 0), 31), pc0 = min(max(c1 - 2, 0), 31);
    uint2 pf = Ab[(size_t)(pr0 * 32 + pc0) * 256 + tid];

    __syncthreads();
    int buf = 0;

#pragma unroll 1
    for (int tp = 0; tp < 25; ++tp) {
        int tr = tp / 5, tc = tp - tr * 5;
        int apr = r1 + tr - 2, apc = c1 + tc - 2;
        bool valid = ((unsigned)apr < 32u) && ((unsigned)apc < 32u);
        uint2 cur = pf;
        if (tp < 24) {
            int t2 = tp + 1;
            int tr2 = t2 / 5, tc2 = t2 - tr2 * 5;
            int npr = min(max(r1 + tr2 - 2, 0), 31);
            int npc = min(max(c1 + tc2 - 2, 0), 31);
            pf = Ab[(size_t)(npr * 32 + npc) * 256 + tid];
        }
        if (!valid) continue;

        uint4 w4a = wsrc[tp * 4 + 0];
        uint4 w4b = wsrc[tp * 4 + 1];
        uint4 w4c = wsrc[tp * 4 + 2];
        uint4 w4d = wsrc[tp * 4 + 3];

        unsigned* hb = (unsigned*)halo[buf];
        hb[dstw] = cur.x;
        hb[dstw + 1] = cur.y;
        __syncthreads();

        unsigned wr[16] = {w4a.x, w4a.y, w4a.z, w4a.w, w4b.x, w4b.y, w4b.z, w4b.w,
                           w4c.x, w4c.y, w4c.z, w4c.w, w4d.x, w4d.y, w4d.z, w4d.w};
        const unsigned* hbr = (const unsigned*)halo[buf];
#pragma unroll
        for (int u = 0; u < 5; ++u) {
            const unsigned* dp = hbr + (qr + u) * 40 + 2 * qc;
            uint2 d01 = *(const uint2*)dp;
            uint2 d23 = *(const uint2*)(dp + 2);
            unsigned u4v = dp[4];
            unsigned u0 = d01.x, u1v = d01.y, u2v = d23.x, u3v = d23.y;
            unsigned o0 = (u0 >> 16) | (u1v << 16);
            unsigned o1 = (u1v >> 16) | (u2v << 16);
            unsigned o2 = (u2v >> 16) | (u3v << 16);
            unsigned o3 = (u3v >> 16) | (u4v << 16);
            acc0 = fdot2(wr[u * 3 + 0], u0, acc0);
            acc0 = fdot2(wr[u * 3 + 1], u1v, acc0);
            acc0 = fdot2(wr[u * 3 + 2], u2v, acc0);
            acc1 = fdot2(wr[u * 3 + 0], o0, acc1);
            acc1 = fdot2(wr[u * 3 + 1], o1, acc1);
            acc1 = fdot2(wr[u * 3 + 2], o2, acc1);
            acc2 = fdot2(wr[u * 3 + 0], u1v, acc2);
            acc2 = fdot2(wr[u * 3 + 1], u2v, acc2);
            acc2 = fdot2(wr[u * 3 + 2], u3v, acc2);
            acc3 = fdot2(wr[u * 3 + 0], o1, acc3);
            acc3 = fdot2(wr[u * 3 + 1], o2, acc3);
            acc3 = fdot2(wr[u * 3 + 2], o3, acc3);
        }
        buf ^= 1;
    }

    float4 res = make_float4(acc0 + bias, acc1 + bias, acc2 + bias, acc3 + bias);
    *(float4*)&xc[((size_t)b * HW + P) * HW + qr * 32 + 4 * qc] = res;
}

// ---- expand: zero-padded copy Apad[b][plane][36][40] (f16)
__global__ __launch_bounds__(256) void expand_kernel(const unsigned short* __restrict__ Af16,
                                                     unsigned* __restrict__ Apad32) {
    int plane = blockIdx.x, b = blockIdx.y;
    const unsigned* src = (const unsigned*)(Af16 + ((size_t)b * HW + plane) * HW);
    unsigned* dst = Apad32 + ((size_t)b * HW + plane) * 720;
    for (int k = threadIdx.x; k < 720; k += 256) {
        int pr = k / 20, pcd = k - pr * 20;
        unsigned val = 0;
        if (pr >= 2 && pr < 34 && pcd >= 1 && pcd <= 16)
            val = src[(pr - 2) * 16 + (pcd - 1)];
        dst[k] = val;
    }
}

// ---- boundary fixup, barrier-free
__global__ __launch_bounds__(128) void fix_kernel(const unsigned* __restrict__ Apad32,
                                                  const unsigned* __restrict__ Wpk,
                                                  const float* __restrict__ BT,
                                                  float* __restrict__ xc) {
    __shared__ __align__(16) unsigned wl[3600];
    __shared__ float bts[9];
    int tid = threadIdx.x;
    int P = blockIdx.x, b = blockIdx.y;
    int r1 = P >> 5, c1 = P & 31;
    int r1c = (r1 == 0) ? 0 : (r1 == 31) ? 2 : 1;
    int c1c = (c1 == 0) ? 0 : (c1 == 31) ? 2 : 1;

    const unsigned* wsrc = Wpk + (size_t)(r1c * 3 + c1c) * 3600;
    for (int i = tid; i < 3600; i += 128) wl[i] = wsrc[i];
    if (tid < 9) bts[tid] = BT[r1 * 27 + c1c * 9 + tid];

    int li = tid;
    bool act = li < 124;
    int qr, qc;
    if (li < 32) { qr = 0; qc = li; }
    else if (li < 64) { qr = 31; qc = li - 32; }
    else if (li < 94) { qr = li - 63; qc = 0; }
    else { qr = min(li, 123) - 93; qc = 31; }
    int r2c = (qr == 0) ? 0 : (qr == 31) ? 2 : 1;
    int c2c = (qc == 0) ? 0 : (qc == 31) ? 2 : 1;
    int v = r2c * 3 + c2c;
    int sh = (qc & 1) * 16;
    int sd = qc >> 1;

    __syncthreads();
    float acc = 0.f;

#pragma unroll 1
    for (int tp = 0; tp < 25; ++tp) {
        int tr = tp / 5, tc = tp - tr * 5;
        int apr = r1 + tr - 2, apc = c1 + tc - 2;
        if ((unsigned)apr >= 32u || (unsigned)apc >= 32u) continue;
        const unsigned* tpl = Apad32 + ((size_t)b * HW + apr * 32 + apc) * 720;
        const uint4* wv4 = (const uint4*)&wl[v * 400 + tp * 16];
        uint4 wa = wv4[0], wb = wv4[1], wc2 = wv4[2], wd = wv4[3];
        unsigned wr[16] = {wa.x, wa.y, wa.z, wa.w, wb.x, wb.y, wb.z, wb.w,
                           wc2.x, wc2.y, wc2.z, wc2.w, wd.x, wd.y, wd.z, wd.w};
#pragma unroll
        for (int u = 0; u < 5; ++u) {
            const unsigned* rp = tpl + (qr + u) * 20 + sd;
            unsigned d0 = rp[0], d1 = rp[1], d2 = rp[2];
            unsigned pa = __builtin_amdgcn_alignbit(d1, d0, sh);
            unsigned pb = __builtin_amdgcn_alignbit(d2, d1, sh);
            unsigned pc_ = __builtin_amdgcn_alignbit(0u, d2, sh);
            acc = fdot2(wr[u * 3 + 0], pa, acc);
            acc = fdot2(wr[u * 3 + 1], pb, acc);
            acc = fdot2(wr[u * 3 + 2], pc_, acc);
        }
    }

    if (act)
        xc[((size_t)b * HW + P) * HW + qr * 32 + qc] = acc + bts[v];
}

__device__ __forceinline__ void top3_push(float v, float& t0, float& t1, float& t2) {
    float n0 = fminf(t0, v);
    t0 = fmaxf(t0, v);
    float n1 = fminf(t1, n0);
    t1 = fmaxf(t1, n0);
    t2 = fmaxf(t2, n1);
}

__global__ __launch_bounds__(256) void topk1_kernel(const float* __restrict__ xc,
                                                    float* __restrict__ part) {
    int q = blockIdx.x * 256 + threadIdx.x;
    int pc = blockIdx.y, bi = blockIdx.z;
    float t0 = -1e30f, t1 = -1e30f, t2 = -1e30f;
    const float* xp = xc + (size_t)bi * HW * HW;
    for (int p = pc * 32; p < pc * 32 + 32; ++p)
        top3_push(xp[(size_t)p * HW + q], t0, t1, t2);
    float* pp = part + (size_t)(bi * 32 + pc) * 3 * HW;
    pp[q] = t0;
    pp[HW + q] = t1;
    pp[2 * HW + q] = t2;
}

__global__ __launch_bounds__(256) void topk2_kernel(const float* __restrict__ part,
                                                    float* __restrict__ out) {
    int q = blockIdx.x * 256 + threadIdx.x;
    int bi = blockIdx.y;
    float t0 = -1e30f, t1 = -1e30f, t2 = -1e30f;
    const float* pp = part + (size_t)bi * 96 * HW;
    for (int k = 0; k < 96; ++k) top3_push(pp[(size_t)k * HW + q], t0, t1, t2);
    float* ob = out + (size_t)bi * 3 * HW;
    ob[q] = t0;
    ob[HW + q] = t1;
    ob[2 * HW + q] = t2;
}

extern "C" void kernel_launch(void* const* d_in, const int* in_sizes, int n_in,
                              void* d_out, int out_size, void* d_ws, size_t ws_size,
                              hipStream_t stream) {
    const float* x = (const float*)d_in[0];
    const float* w1 = (const float*)d_in[1];
    const float* b1 = (const float*)d_in[2];
    const float* w2 = (const float*)d_in[3];
    const float* b2 = (const float*)d_in[4];
    float* out = (float*)d_out;
    float* ws = (float*)d_ws;

    unsigned short* xnT = (unsigned short*)ws;
    unsigned short* Af16 = (unsigned short*)(ws + 524288);
    float* xc = ws + 2621440;
    unsigned* Wpk = (unsigned*)(ws + 6815744);
    float* BT = ws + 6848512;
    float* part = ws + 6849536;
    unsigned* Apad32 = (unsigned*)(ws + 7242752);
    float* G = ws + 10191872;

    norm_kernel<<<dim3(64, 4), 256, 0, stream>>>(x, xnT);
    aff_kernel<<<dim3(16, 16, 4), 256, 0, stream>>>(xnT, Af16);
    expand_kernel<<<dim3(1024, 4), 256, 0, stream>>>(Af16, Apad32);
    g_kernel<<<26, 256, 0, stream>>>(w1, w2, G);
    wcomp_kernel<<<81, 128, 0, stream>>>(G, Wpk);
    bt_kernel<<<1, 1024, 0, stream>>>(w2, b1, b2, BT);
    convc_kernel<<<dim3(1024, 4), 256, 0, stream>>>(Af16, Wpk, BT, xc);
    fix_kernel<<<dim3(1024, 4), 128, 0, stream>>>(Apad32, Wpk, BT, xc);
    topk1_kernel<<<dim3(4, 32, 4), 256, 0, stream>>>(xc, part);
    topk2_kernel<<<dim3(4, 4), 256, 0, stream>>>(part, out);
}

// Round 12
// 178.015 us; speedup vs baseline: 2.3301x; 1.0381x over previous
//
#include <hip/hip_runtime.h>

#define HW 1024
#define CCH 256

// ws layout (f32 units):
//   xnT : bf16 [4][1024][256]       off 0            524,288
//   Af16: f16  [4][1024][1024]      off 524,288    2,097,152
//   xc  : f32  [4][1024][1024]      off 2,621,440  4,194,304
//   Wpk : u32  [81][25][16]         off 6,815,744     32,400
//   BT  : f32  [32][3][3][3]        off 6,848,512        864
//   part: f32  [4][32][3][1024]     off 6,849,536    393,216
//   Apad: f16  [4][1024][36][40]    off 7,242,752  2,949,120
//   G   : f32  [81][81]             off 10,191,872      6,561

typedef _Float16 h2v __attribute__((ext_vector_type(2)));
typedef short bf16x8 __attribute__((ext_vector_type(8)));
typedef float f32x4 __attribute__((ext_vector_type(4)));

__device__ __forceinline__ float fdot2(unsigned a, unsigned b, float c) {
#if __has_builtin(__builtin_amdgcn_fdot2)
    return __builtin_amdgcn_fdot2(__builtin_bit_cast(h2v, a),
                                  __builtin_bit_cast(h2v, b), c, false);
#else
    h2v ha = __builtin_bit_cast(h2v, a), hb = __builtin_bit_cast(h2v, b);
    return c + (float)ha.x * (float)hb.x + (float)ha.y * (float)hb.y;
#endif
}
__device__ __forceinline__ unsigned packh2(float x, float y) {
    h2v h;
    h.x = (_Float16)x;
    h.y = (_Float16)y;
    return __builtin_bit_cast(unsigned, h);
}
__device__ __forceinline__ unsigned short f2bf(float f) {
    unsigned u = __float_as_uint(f);
    u += 0x7fffu + ((u >> 16) & 1u);
    return (unsigned short)(u >> 16);
}

// ---- norm
__global__ __launch_bounds__(256) void norm_kernel(const float* __restrict__ x,
                                                   unsigned short* __restrict__ xnT) {
    __shared__ float red[16][17];
    __shared__ float invs[16];
    int b = blockIdx.y;
    int p0 = blockIdx.x * 16;
    int cg = threadIdx.x >> 4;
    int pp = threadIdx.x & 15;
    int p = p0 + pp;
    const float* xb = x + (size_t)b * CCH * HW;
    float ss = 0.f;
#pragma unroll
    for (int i = 0; i < 16; ++i) {
        float v = xb[(size_t)(cg * 16 + i) * HW + p];
        ss += v * v;
    }
    red[cg][pp] = ss;
    __syncthreads();
    if (threadIdx.x < 16) {
        float s = 0.f;
#pragma unroll
        for (int g = 0; g < 16; ++g) s += red[g][threadIdx.x];
        invs[threadIdx.x] = 1.0f / fmaxf(sqrtf(s), 1e-12f);
    }
    __syncthreads();
    float inv = invs[pp];
    unsigned* o = (unsigned*)(xnT + ((size_t)b * HW + p) * CCH) + cg * 8;
#pragma unroll
    for (int i = 0; i < 8; ++i) {
        int c = cg * 16 + 2 * i;
        unsigned lo = f2bf(xb[(size_t)c * HW + p] * inv);
        unsigned hi = f2bf(xb[(size_t)(c + 1) * HW + p] * inv);
        o[i] = lo | (hi << 16);
    }
}

// ---- aff (bf16 MFMA)
__global__ __launch_bounds__(256) void aff_kernel(const unsigned short* __restrict__ xnT,
                                                  unsigned short* __restrict__ Af16) {
    int b = blockIdx.z;
    int p0 = blockIdx.y * 64, m0 = blockIdx.x * 64;
    const unsigned short* X = xnT + (size_t)b * HW * CCH;
    int lane = threadIdx.x & 63, w = threadIdx.x >> 6;
    int pw = p0 + (w >> 1) * 32, mw = m0 + (w & 1) * 32;
    int lr = lane & 15, lg = lane >> 4;
    f32x4 acc[2][2] = {};
    for (int ks = 0; ks < 8; ++ks) {
        int kc = ks * 32 + lg * 8;
        bf16x8 a0 = *(const bf16x8*)&X[(size_t)(pw + lr) * CCH + kc];
        bf16x8 a1 = *(const bf16x8*)&X[(size_t)(pw + 16 + lr) * CCH + kc];
        bf16x8 b0 = *(const bf16x8*)&X[(size_t)(mw + lr) * CCH + kc];
        bf16x8 b1 = *(const bf16x8*)&X[(size_t)(mw + 16 + lr) * CCH + kc];
        acc[0][0] = __builtin_amdgcn_mfma_f32_16x16x32_bf16(a0, b0, acc[0][0], 0, 0, 0);
        acc[0][1] = __builtin_amdgcn_mfma_f32_16x16x32_bf16(a0, b1, acc[0][1], 0, 0, 0);
        acc[1][0] = __builtin_amdgcn_mfma_f32_16x16x32_bf16(a1, b0, acc[1][0], 0, 0, 0);
        acc[1][1] = __builtin_amdgcn_mfma_f32_16x16x32_bf16(a1, b1, acc[1][1], 0, 0, 0);
    }
#pragma unroll
    for (int pi = 0; pi < 2; ++pi)
#pragma unroll
        for (int mi = 0; mi < 2; ++mi)
#pragma unroll
            for (int r = 0; r < 4; ++r) {
                int p = pw + 16 * pi + lg * 4 + r;
                int m = mw + 16 * mi + lr;
                int dr = (m >> 5) - (p >> 5);
                int dc = (m & 31) - (p & 31);
                float gg = 1.0f - __expf(-(float)(dr * dr + dc * dc) * 0.1953125f);
                float v = acc[pi][mi][r] * gg;
                Af16[((size_t)b * HW + p) * HW + m] =
                    __builtin_bit_cast(unsigned short, (_Float16)v);
            }
}

// ---- G[o1][o2] = sum_ch w1[ch][o1]*w2[ch][o2]
__global__ __launch_bounds__(256) void g_kernel(const float* __restrict__ w1,
                                                const float* __restrict__ w2,
                                                float* __restrict__ G) {
    __shared__ float w1s[1296], w2s[1296];
    int tid = threadIdx.x;
    for (int i = tid; i < 1296; i += 256) { w1s[i] = w1[i]; w2s[i] = w2[i]; }
    __syncthreads();
    int idx = blockIdx.x * 256 + tid;
    if (idx < 6561) {
        int o1 = idx / 81, o2 = idx - o1 * 81;
        float s = 0.f;
#pragma unroll
        for (int ch = 0; ch < 16; ++ch) s += w1s[ch * 81 + o1] * w2s[ch * 81 + o2];
        G[idx] = s;
    }
}

// ---- wcomp from G
__global__ __launch_bounds__(128) void wcomp_kernel(const float* __restrict__ G,
                                                    unsigned* __restrict__ Wpk) {
    __shared__ float Gs[6561];
    int cls = blockIdx.x;
    int t = threadIdx.x;
    for (int i = t; i < 6561; i += 128) Gs[i] = G[i];
    if (t < 25) Wpk[cls * 400 + t * 16 + 15] = 0u;
    __syncthreads();
    if (t >= 125) return;
    int a = t / 25, b_ = (t / 5) % 5, c = t % 5;
    int r1c = cls / 27, c1c = (cls / 9) % 3, r2c = (cls / 3) % 3, c2c = cls % 3;
    float W[5] = {};
    for (int i2 = 0; i2 < 3; ++i2) {
        if ((r1c == 0 && i2 == 0) || (r1c == 2 && i2 == 2)) continue;
        int i1 = a - i2;
        if (i1 < 0 || i1 > 2) continue;
        for (int j2 = 0; j2 < 3; ++j2) {
            if ((c1c == 0 && j2 == 0) || (c1c == 2 && j2 == 2)) continue;
            int j1 = b_ - j2;
            if (j1 < 0 || j1 > 2) continue;
            for (int u2 = 0; u2 < 3; ++u2) {
                if ((r2c == 0 && u2 == 0) || (r2c == 2 && u2 == 2)) continue;
                int u1 = c - u2;
                if (u1 < 0 || u1 > 2) continue;
                for (int v2 = 0; v2 < 3; ++v2) {
                    if ((c2c == 0 && v2 == 0) || (c2c == 2 && v2 == 2)) continue;
                    int o2 = i2 * 27 + j2 * 9 + u2 * 3 + v2;
                    int o1b = i1 * 27 + j1 * 9 + u1 * 3;
#pragma unroll
                    for (int d = 0; d < 5; ++d) {
                        int v1 = d - v2;
                        if (v1 < 0 || v1 > 2) continue;
                        W[d] += Gs[(o1b + v1) * 81 + o2];
                    }
                }
            }
        }
    }
    unsigned* o = &Wpk[cls * 400 + (a * 5 + b_) * 16 + c * 3];
    o[0] = packh2(W[0], W[1]);
    o[1] = packh2(W[2], W[3]);
    o[2] = packh2(W[4], 0.f);
}

// ---- bt via S-tables, single block
__global__ __launch_bounds__(1024) void bt_kernel(const float* __restrict__ w2,
                                                  const float* __restrict__ b1,
                                                  const float* __restrict__ b2,
                                                  float* __restrict__ BT) {
    __shared__ float w2s[1296], b1s[48], S0[81], S1[81], S2[81];
    int t = threadIdx.x;
    for (int i = t; i < 1296; i += 1024) w2s[i] = w2[i];
    if (t < 48) b1s[t] = b1[t];
    __syncthreads();
    if (t < 81) {
        float s0 = 0.f, s1 = 0.f, s2 = 0.f;
#pragma unroll
        for (int ch = 0; ch < 16; ++ch) {
            float w = w2s[ch * 81 + t];
            s0 += w * b1s[16 + ch];
            s1 += w * b1s[ch];
            s2 += w * b1s[32 + ch];
        }
        S0[t] = s0; S1[t] = s1; S2[t] = s2;
    }
    __syncthreads();
    if (t >= 864) return;
    int r1 = t / 27, c1c = (t / 9) % 3, r2c = (t / 3) % 3, c2c = t % 3;
    float s = b2[1] + (r1 >= 1 ? b2[0] : 0.f) + (r1 <= 30 ? b2[2] : 0.f);
    for (int i2 = 0; i2 < 3; ++i2) {
        int rr = r1 + i2 - 1;
        if (rr < 0 || rr > 31) continue;
        float m1 = (rr >= 1) ? 1.f : 0.f, m2 = (rr <= 30) ? 1.f : 0.f;
        for (int j2 = 0; j2 < 3; ++j2) {
            if ((c1c == 0 && j2 == 0) || (c1c == 2 && j2 == 2)) continue;
            for (int u2 = 0; u2 < 3; ++u2) {
                if ((r2c == 0 && u2 == 0) || (r2c == 2 && u2 == 2)) continue;
                for (int v2 = 0; v2 < 3; ++v2) {
                    if ((c2c == 0 && v2 == 0) || (c2c == 2 && v2 == 2)) continue;
                    int o2 = i2 * 27 + j2 * 9 + u2 * 3 + v2;
                    s += S0[o2] + m1 * S1[o2] + m2 * S2[o2];
                }
            }
        }
    }
    BT[t] = s;
}

// ---- main composed conv: 64-thr (1 wave) per plane, 16 px/thread (2r x 8c).
// Halo: stride 56 dwords, slot = col+2 (dword shift = +1 after 8t offset).
#define HSD 56
__global__ __launch_bounds__(64) void convc_kernel(const unsigned short* __restrict__ Af16,
                                                   const unsigned* __restrict__ Wpk,
                                                   const float* __restrict__ BT,
                                                   float* __restrict__ xc) {
    __shared__ unsigned halo[36 * HSD];  // 8064 B
    int tid = threadIdx.x;
    int P = blockIdx.x, b = blockIdx.y;
    int r1 = P >> 5, c1 = P & 31;
    int r1c = (r1 == 0) ? 0 : (r1 == 31) ? 2 : 1;
    int c1c = (c1 == 0) ? 0 : (c1 == 31) ? 2 : 1;

    const uint4* wsrc = (const uint4*)(Wpk + (size_t)((r1c * 3 + c1c) * 9 + 4) * 400);
    float bias = BT[r1 * 27 + c1c * 9 + 4];

    for (int i = tid; i < 36 * HSD; i += 64) halo[i] = 0;

    int qr2 = tid >> 2;      // rows 2qr2, 2qr2+1
    int qc = tid & 3;        // cols 8qc..8qc+7
    int srow = tid >> 1;     // staging row
    int st = tid & 1;        // staging col half
    int wbase = (srow + 2) * HSD + 8 * st + 1;

    const uint4* Ab4 = (const uint4*)(Af16 + (size_t)b * HW * HW);

    float acc0[8] = {}, acc1[8] = {};

    int pr0 = min(max(r1 - 2, 0), 31), pc0 = min(max(c1 - 2, 0), 31);
    uint4 pfA = Ab4[(size_t)(pr0 * 32 + pc0) * 128 + 2 * tid];
    uint4 pfB = Ab4[(size_t)(pr0 * 32 + pc0) * 128 + 2 * tid + 1];

    __syncthreads();

#pragma unroll 1
    for (int tp = 0; tp < 25; ++tp) {
        int tr = tp / 5, tc = tp - tr * 5;
        int apr = r1 + tr - 2, apc = c1 + tc - 2;
        bool valid = ((unsigned)apr < 32u) && ((unsigned)apc < 32u);
        uint4 curA = pfA, curB = pfB;
        if (tp < 24) {
            int t2 = tp + 1;
            int tr2 = t2 / 5, tc2 = t2 - tr2 * 5;
            int npr = min(max(r1 + tr2 - 2, 0), 31);
            int npc = min(max(c1 + tc2 - 2, 0), 31);
            pfA = Ab4[(size_t)(npr * 32 + npc) * 128 + 2 * tid];
            pfB = Ab4[(size_t)(npr * 32 + npc) * 128 + 2 * tid + 1];
        }
        if (!valid) continue;

        uint4 w4a = wsrc[tp * 4 + 0];
        uint4 w4b = wsrc[tp * 4 + 1];
        uint4 w4c = wsrc[tp * 4 + 2];
        uint4 w4d = wsrc[tp * 4 + 3];

        __syncthreads();  // WAR vs previous tap's reads (1 wave: cheap)
        {
            unsigned* hb = &halo[wbase];
            hb[0] = curA.x; hb[1] = curA.y; hb[2] = curA.z; hb[3] = curA.w;
            hb[4] = curB.x; hb[5] = curB.y; hb[6] = curB.z; hb[7] = curB.w;
        }
        __syncthreads();  // RAW

        unsigned wr[16] = {w4a.x, w4a.y, w4a.z, w4a.w, w4b.x, w4b.y, w4b.z, w4b.w,
                           w4c.x, w4c.y, w4c.z, w4c.w, w4d.x, w4d.y, w4d.z, w4d.w};
        const unsigned* base = &halo[(2 * qr2) * HSD + 4 * qc];
#pragma unroll
        for (int i = 0; i < 6; ++i) {
            const unsigned* rp = base + i * HSD;
            uint2 e0 = *(const uint2*)rp;
            uint2 e1 = *(const uint2*)(rp + 2);
            uint2 e2 = *(const uint2*)(rp + 4);
            unsigned q0 = e0.x, q1 = e0.y, q2 = e1.x, q3 = e1.y, q4 = e2.x, q5 = e2.y;
            unsigned pp[12];
            pp[0] = q0;  pp[2] = q1;  pp[4] = q2;  pp[6] = q3;  pp[8] = q4;  pp[10] = q5;
            pp[1] = (q0 >> 16) | (q1 << 16);
            pp[3] = (q1 >> 16) | (q2 << 16);
            pp[5] = (q2 >> 16) | (q3 << 16);
            pp[7] = (q3 >> 16) | (q4 << 16);
            pp[9] = (q4 >> 16) | (q5 << 16);
            pp[11] = (q5 >> 16);
            if (i <= 4) {
                unsigned wa = wr[i * 3], wb_ = wr[i * 3 + 1], wc_ = wr[i * 3 + 2];
#pragma unroll
                for (int cc = 0; cc < 8; ++cc) {
                    float a = acc0[cc];
                    a = fdot2(wa, pp[cc], a);
                    a = fdot2(wb_, pp[cc + 2], a);
                    a = fdot2(wc_, pp[cc + 4], a);
                    acc0[cc] = a;
                }
            }
            if (i >= 1) {
                int u = i - 1;
                unsigned wa = wr[u * 3], wb_ = wr[u * 3 + 1], wc_ = wr[u * 3 + 2];
#pragma unroll
                for (int cc = 0; cc < 8; ++cc) {
                    float a = acc1[cc];
                    a = fdot2(wa, pp[cc], a);
                    a = fdot2(wb_, pp[cc + 2], a);
                    a = fdot2(wc_, pp[cc + 4], a);
                    acc1[cc] = a;
                }
            }
        }
    }

    float* xp = &xc[((size_t)b * HW + P) * HW];
    int o0 = (2 * qr2) * 32 + 8 * qc;
    int o1 = (2 * qr2 + 1) * 32 + 8 * qc;
    *(float4*)&xp[o0] = make_float4(acc0[0] + bias, acc0[1] + bias, acc0[2] + bias, acc0[3] + bias);
    *(float4*)&xp[o0 + 4] = make_float4(acc0[4] + bias, acc0[5] + bias, acc0[6] + bias, acc0[7] + bias);
    *(float4*)&xp[o1] = make_float4(acc1[0] + bias, acc1[1] + bias, acc1[2] + bias, acc1[3] + bias);
    *(float4*)&xp[o1 + 4] = make_float4(acc1[4] + bias, acc1[5] + bias, acc1[6] + bias, acc1[7] + bias);
}

// ---- expand: zero-padded copy Apad[b][plane][36][40] (f16)
__global__ __launch_bounds__(256) void expand_kernel(const unsigned short* __restrict__ Af16,
                                                     unsigned* __restrict__ Apad32) {
    int plane = blockIdx.x, b = blockIdx.y;
    const unsigned* src = (const unsigned*)(Af16 + ((size_t)b * HW + plane) * HW);
    unsigned* dst = Apad32 + ((size_t)b * HW + plane) * 720;
    for (int k = threadIdx.x; k < 720; k += 256) {
        int pr = k / 20, pcd = k - pr * 20;
        unsigned val = 0;
        if (pr >= 2 && pr < 34 && pcd >= 1 && pcd <= 16)
            val = src[(pr - 2) * 16 + (pcd - 1)];
        dst[k] = val;
    }
}

// ---- boundary fixup, barrier-free
__global__ __launch_bounds__(128) void fix_kernel(const unsigned* __restrict__ Apad32,
                                                  const unsigned* __restrict__ Wpk,
                                                  const float* __restrict__ BT,
                                                  float* __restrict__ xc) {
    __shared__ __align__(16) unsigned wl[3600];
    __shared__ float bts[9];
    int tid = threadIdx.x;
    int P = blockIdx.x, b = blockIdx.y;
    int r1 = P >> 5, c1 = P & 31;
    int r1c = (r1 == 0) ? 0 : (r1 == 31) ? 2 : 1;
    int c1c = (c1 == 0) ? 0 : (c1 == 31) ? 2 : 1;

    const unsigned* wsrc = Wpk + (size_t)(r1c * 3 + c1c) * 3600;
    for (int i = tid; i < 3600; i += 128) wl[i] = wsrc[i];
    if (tid < 9) bts[tid] = BT[r1 * 27 + c1c * 9 + tid];

    int li = tid;
    bool act = li < 124;
    int qr, qc;
    if (li < 32) { qr = 0; qc = li; }
    else if (li < 64) { qr = 31; qc = li - 32; }
    else if (li < 94) { qr = li - 63; qc = 0; }
    else { qr = min(li, 123) - 93; qc = 31; }
    int r2c = (qr == 0) ? 0 : (qr == 31) ? 2 : 1;
    int c2c = (qc == 0) ? 0 : (qc == 31) ? 2 : 1;
    int v = r2c * 3 + c2c;
    int sh = (qc & 1) * 16;
    int sd = qc >> 1;

    __syncthreads();
    float acc = 0.f;

#pragma unroll 1
    for (int tp = 0; tp < 25; ++tp) {
        int tr = tp / 5, tc = tp - tr * 5;
        int apr = r1 + tr - 2, apc = c1 + tc - 2;
        if ((unsigned)apr >= 32u || (unsigned)apc >= 32u) continue;
        const unsigned* tpl = Apad32 + ((size_t)b * HW + apr * 32 + apc) * 720;
        const uint4* wv4 = (const uint4*)&wl[v * 400 + tp * 16];
        uint4 wa = wv4[0], wb = wv4[1], wc2 = wv4[2], wd = wv4[3];
        unsigned wr[16] = {wa.x, wa.y, wa.z, wa.w, wb.x, wb.y, wb.z, wb.w,
                           wc2.x, wc2.y, wc2.z, wc2.w, wd.x, wd.y, wd.z, wd.w};
#pragma unroll
        for (int u = 0; u < 5; ++u) {
            const unsigned* rp = tpl + (qr + u) * 20 + sd;
            unsigned d0 = rp[0], d1 = rp[1], d2 = rp[2];
            unsigned pa = __builtin_amdgcn_alignbit(d1, d0, sh);
            unsigned pb = __builtin_amdgcn_alignbit(d2, d1, sh);
            unsigned pc_ = __builtin_amdgcn_alignbit(0u, d2, sh);
            acc = fdot2(wr[u * 3 + 0], pa, acc);
            acc = fdot2(wr[u * 3 + 1], pb, acc);
            acc = fdot2(wr[u * 3 + 2], pc_, acc);
        }
    }

    if (act)
        xc[((size_t)b * HW + P) * HW + qr * 32 + qc] = acc + bts[v];
}

__device__ __forceinline__ void top3_push(float v, float& t0, float& t1, float& t2) {
    float n0 = fminf(t0, v);
    t0 = fmaxf(t0, v);
    float n1 = fminf(t1, n0);
    t1 = fmaxf(t1, n0);
    t2 = fmaxf(t2, n1);
}

__global__ __launch_bounds__(256) void topk1_kernel(const float* __restrict__ xc,
                                                    float* __restrict__ part) {
    int q = blockIdx.x * 256 + threadIdx.x;
    int pc = blockIdx.y, bi = blockIdx.z;
    float t0 = -1e30f, t1 = -1e30f, t2 = -1e30f;
    const float* xp = xc + (size_t)bi * HW * HW;
    for (int p = pc * 32; p < pc * 32 + 32; ++p)
        top3_push(xp[(size_t)p * HW + q], t0, t1, t2);
    float* pp = part + (size_t)(bi * 32 + pc) * 3 * HW;
    pp[q] = t0;
    pp[HW + q] = t1;
    pp[2 * HW + q] = t2;
}

__global__ __launch_bounds__(256) void topk2_kernel(const float* __restrict__ part,
                                                    float* __restrict__ out) {
    int q = blockIdx.x * 256 + threadIdx.x;
    int bi = blockIdx.y;
    float t0 = -1e30f, t1 = -1e30f, t2 = -1e30f;
    const float* pp = part + (size_t)bi * 96 * HW;
    for (int k = 0; k < 96; ++k) top3_push(pp[(size_t)k * HW + q], t0, t1, t2);
    float* ob = out + (size_t)bi * 3 * HW;
    ob[q] = t0;
    ob[HW + q] = t1;
    ob[2 * HW + q] = t2;
}

extern "C" void kernel_launch(void* const* d_in, const int* in_sizes, int n_in,
                              void* d_out, int out_size, void* d_ws, size_t ws_size,
                              hipStream_t stream) {
    const float* x = (const float*)d_in[0];
    const float* w1 = (const float*)d_in[1];
    const float* b1 = (const float*)d_in[2];
    const float* w2 = (const float*)d_in[3];
    const float* b2 = (const float*)d_in[4];
    float* out = (float*)d_out;
    float* ws = (float*)d_ws;

    unsigned short* xnT = (unsigned short*)ws;
    unsigned short* Af16 = (unsigned short*)(ws + 524288);
    float* xc = ws + 2621440;
    unsigned* Wpk = (unsigned*)(ws + 6815744);
    float* BT = ws + 6848512;
    float* part = ws + 6849536;
    unsigned* Apad32 = (unsigned*)(ws + 7242752);
    float* G = ws + 10191872;

    norm_kernel<<<dim3(64, 4), 256, 0, stream>>>(x, xnT);
    aff_kernel<<<dim3(16, 16, 4), 256, 0, stream>>>(xnT, Af16);
    expand_kernel<<<dim3(1024, 4), 256, 0, stream>>>(Af16, Apad32);
    g_kernel<<<26, 256, 0, stream>>>(w1, w2, G);
    wcomp_kernel<<<81, 128, 0, stream>>>(G, Wpk);
    bt_kernel<<<1, 1024, 0, stream>>>(w2, b1, b2, BT);
    convc_kernel<<<dim3(1024, 4), 64, 0, stream>>>(Af16, Wpk, BT, xc);
    fix_kernel<<<dim3(1024, 4), 128, 0, stream>>>(Apad32, Wpk, BT, xc);
    topk1_kernel<<<dim3(4, 32, 4), 256, 0, stream>>>(xc, part);
    topk2_kernel<<<dim3(4, 4), 256, 0, stream>>>(part, out);
}

// Round 13
// 175.120 us; speedup vs baseline: 2.3687x; 1.0165x over previous
//
#include <hip/hip_runtime.h>

#define HW 1024
#define CCH 256

// ws layout (f32 units):
//   xnT : bf16 [4][1024][256]       off 0            524,288
//   Af16: f16  [4][1024][1024]      off 524,288    2,097,152
//   xc  : f32  [4][1024][1024]      off 2,621,440  4,194,304
//   Wpk : u32  [81][25][16]         off 6,815,744     32,400
//   BT  : f32  [32][3][3][3]        off 6,848,512        864
//   part: f32  [4][32][3][1024]     off 6,849,536    393,216
//   Apad: f16  [4][1024][36][40]    off 7,242,752  2,949,120
//   G   : f32  [81][81]             off 10,191,872      6,561

typedef _Float16 h2v __attribute__((ext_vector_type(2)));
typedef short bf16x8 __attribute__((ext_vector_type(8)));
typedef float f32x4 __attribute__((ext_vector_type(4)));

__device__ __forceinline__ float fdot2(unsigned a, unsigned b, float c) {
#if __has_builtin(__builtin_amdgcn_fdot2)
    return __builtin_amdgcn_fdot2(__builtin_bit_cast(h2v, a),
                                  __builtin_bit_cast(h2v, b), c, false);
#else
    h2v ha = __builtin_bit_cast(h2v, a), hb = __builtin_bit_cast(h2v, b);
    return c + (float)ha.x * (float)hb.x + (float)ha.y * (float)hb.y;
#endif
}
__device__ __forceinline__ unsigned packh2(float x, float y) {
    h2v h;
    h.x = (_Float16)x;
    h.y = (_Float16)y;
    return __builtin_bit_cast(unsigned, h);
}
__device__ __forceinline__ unsigned short f2bf(float f) {
    unsigned u = __float_as_uint(f);
    u += 0x7fffu + ((u >> 16) & 1u);
    return (unsigned short)(u >> 16);
}

// ---- norm
__global__ __launch_bounds__(256) void norm_kernel(const float* __restrict__ x,
                                                   unsigned short* __restrict__ xnT) {
    __shared__ float red[16][17];
    __shared__ float invs[16];
    int b = blockIdx.y;
    int p0 = blockIdx.x * 16;
    int cg = threadIdx.x >> 4;
    int pp = threadIdx.x & 15;
    int p = p0 + pp;
    const float* xb = x + (size_t)b * CCH * HW;
    float ss = 0.f;
#pragma unroll
    for (int i = 0; i < 16; ++i) {
        float v = xb[(size_t)(cg * 16 + i) * HW + p];
        ss += v * v;
    }
    red[cg][pp] = ss;
    __syncthreads();
    if (threadIdx.x < 16) {
        float s = 0.f;
#pragma unroll
        for (int g = 0; g < 16; ++g) s += red[g][threadIdx.x];
        invs[threadIdx.x] = 1.0f / fmaxf(sqrtf(s), 1e-12f);
    }
    __syncthreads();
    float inv = invs[pp];
    unsigned* o = (unsigned*)(xnT + ((size_t)b * HW + p) * CCH) + cg * 8;
#pragma unroll
    for (int i = 0; i < 8; ++i) {
        int c = cg * 16 + 2 * i;
        unsigned lo = f2bf(xb[(size_t)c * HW + p] * inv);
        unsigned hi = f2bf(xb[(size_t)(c + 1) * HW + p] * inv);
        o[i] = lo | (hi << 16);
    }
}

// ---- aff (bf16 MFMA)
__global__ __launch_bounds__(256) void aff_kernel(const unsigned short* __restrict__ xnT,
                                                  unsigned short* __restrict__ Af16) {
    int b = blockIdx.z;
    int p0 = blockIdx.y * 64, m0 = blockIdx.x * 64;
    const unsigned short* X = xnT + (size_t)b * HW * CCH;
    int lane = threadIdx.x & 63, w = threadIdx.x >> 6;
    int pw = p0 + (w >> 1) * 32, mw = m0 + (w & 1) * 32;
    int lr = lane & 15, lg = lane >> 4;
    f32x4 acc[2][2] = {};
    for (int ks = 0; ks < 8; ++ks) {
        int kc = ks * 32 + lg * 8;
        bf16x8 a0 = *(const bf16x8*)&X[(size_t)(pw + lr) * CCH + kc];
        bf16x8 a1 = *(const bf16x8*)&X[(size_t)(pw + 16 + lr) * CCH + kc];
        bf16x8 b0 = *(const bf16x8*)&X[(size_t)(mw + lr) * CCH + kc];
        bf16x8 b1 = *(const bf16x8*)&X[(size_t)(mw + 16 + lr) * CCH + kc];
        acc[0][0] = __builtin_amdgcn_mfma_f32_16x16x32_bf16(a0, b0, acc[0][0], 0, 0, 0);
        acc[0][1] = __builtin_amdgcn_mfma_f32_16x16x32_bf16(a0, b1, acc[0][1], 0, 0, 0);
        acc[1][0] = __builtin_amdgcn_mfma_f32_16x16x32_bf16(a1, b0, acc[1][0], 0, 0, 0);
        acc[1][1] = __builtin_amdgcn_mfma_f32_16x16x32_bf16(a1, b1, acc[1][1], 0, 0, 0);
    }
#pragma unroll
    for (int pi = 0; pi < 2; ++pi)
#pragma unroll
        for (int mi = 0; mi < 2; ++mi)
#pragma unroll
            for (int r = 0; r < 4; ++r) {
                int p = pw + 16 * pi + lg * 4 + r;
                int m = mw + 16 * mi + lr;
                int dr = (m >> 5) - (p >> 5);
                int dc = (m & 31) - (p & 31);
                float gg = 1.0f - __expf(-(float)(dr * dr + dc * dc) * 0.1953125f);
                float v = acc[pi][mi][r] * gg;
                Af16[((size_t)b * HW + p) * HW + m] =
                    __builtin_bit_cast(unsigned short, (_Float16)v);
            }
}

// ---- G[o1][o2] = sum_ch w1[ch][o1]*w2[ch][o2]
__global__ __launch_bounds__(256) void g_kernel(const float* __restrict__ w1,
                                                const float* __restrict__ w2,
                                                float* __restrict__ G) {
    __shared__ float w1s[1296], w2s[1296];
    int tid = threadIdx.x;
    for (int i = tid; i < 1296; i += 256) { w1s[i] = w1[i]; w2s[i] = w2[i]; }
    __syncthreads();
    int idx = blockIdx.x * 256 + tid;
    if (idx < 6561) {
        int o1 = idx / 81, o2 = idx - o1 * 81;
        float s = 0.f;
#pragma unroll
        for (int ch = 0; ch < 16; ++ch) s += w1s[ch * 81 + o1] * w2s[ch * 81 + o2];
        G[idx] = s;
    }
}

// ---- wcomp from G
__global__ __launch_bounds__(128) void wcomp_kernel(const float* __restrict__ G,
                                                    unsigned* __restrict__ Wpk) {
    __shared__ float Gs[6561];
    int cls = blockIdx.x;
    int t = threadIdx.x;
    for (int i = t; i < 6561; i += 128) Gs[i] = G[i];
    if (t < 25) Wpk[cls * 400 + t * 16 + 15] = 0u;
    __syncthreads();
    if (t >= 125) return;
    int a = t / 25, b_ = (t / 5) % 5, c = t % 5;
    int r1c = cls / 27, c1c = (cls / 9) % 3, r2c = (cls / 3) % 3, c2c = cls % 3;
    float W[5] = {};
    for (int i2 = 0; i2 < 3; ++i2) {
        if ((r1c == 0 && i2 == 0) || (r1c == 2 && i2 == 2)) continue;
        int i1 = a - i2;
        if (i1 < 0 || i1 > 2) continue;
        for (int j2 = 0; j2 < 3; ++j2) {
            if ((c1c == 0 && j2 == 0) || (c1c == 2 && j2 == 2)) continue;
            int j1 = b_ - j2;
            if (j1 < 0 || j1 > 2) continue;
            for (int u2 = 0; u2 < 3; ++u2) {
                if ((r2c == 0 && u2 == 0) || (r2c == 2 && u2 == 2)) continue;
                int u1 = c - u2;
                if (u1 < 0 || u1 > 2) continue;
                for (int v2 = 0; v2 < 3; ++v2) {
                    if ((c2c == 0 && v2 == 0) || (c2c == 2 && v2 == 2)) continue;
                    int o2 = i2 * 27 + j2 * 9 + u2 * 3 + v2;
                    int o1b = i1 * 27 + j1 * 9 + u1 * 3;
#pragma unroll
                    for (int d = 0; d < 5; ++d) {
                        int v1 = d - v2;
                        if (v1 < 0 || v1 > 2) continue;
                        W[d] += Gs[(o1b + v1) * 81 + o2];
                    }
                }
            }
        }
    }
    unsigned* o = &Wpk[cls * 400 + (a * 5 + b_) * 16 + c * 3];
    o[0] = packh2(W[0], W[1]);
    o[1] = packh2(W[2], W[3]);
    o[2] = packh2(W[4], 0.f);
}

// ---- bt via S-tables, single block
__global__ __launch_bounds__(1024) void bt_kernel(const float* __restrict__ w2,
                                                  const float* __restrict__ b1,
                                                  const float* __restrict__ b2,
                                                  float* __restrict__ BT) {
    __shared__ float w2s[1296], b1s[48], S0[81], S1[81], S2[81];
    int t = threadIdx.x;
    for (int i = t; i < 1296; i += 1024) w2s[i] = w2[i];
    if (t < 48) b1s[t] = b1[t];
    __syncthreads();
    if (t < 81) {
        float s0 = 0.f, s1 = 0.f, s2 = 0.f;
#pragma unroll
        for (int ch = 0; ch < 16; ++ch) {
            float w = w2s[ch * 81 + t];
            s0 += w * b1s[16 + ch];
            s1 += w * b1s[ch];
            s2 += w * b1s[32 + ch];
        }
        S0[t] = s0; S1[t] = s1; S2[t] = s2;
    }
    __syncthreads();
    if (t >= 864) return;
    int r1 = t / 27, c1c = (t / 9) % 3, r2c = (t / 3) % 3, c2c = t % 3;
    float s = b2[1] + (r1 >= 1 ? b2[0] : 0.f) + (r1 <= 30 ? b2[2] : 0.f);
    for (int i2 = 0; i2 < 3; ++i2) {
        int rr = r1 + i2 - 1;
        if (rr < 0 || rr > 31) continue;
        float m1 = (rr >= 1) ? 1.f : 0.f, m2 = (rr <= 30) ? 1.f : 0.f;
        for (int j2 = 0; j2 < 3; ++j2) {
            if ((c1c == 0 && j2 == 0) || (c1c == 2 && j2 == 2)) continue;
            for (int u2 = 0; u2 < 3; ++u2) {
                if ((r2c == 0 && u2 == 0) || (r2c == 2 && u2 == 2)) continue;
                for (int v2 = 0; v2 < 3; ++v2) {
                    if ((c2c == 0 && v2 == 0) || (c2c == 2 && v2 == 2)) continue;
                    int o2 = i2 * 27 + j2 * 9 + u2 * 3 + v2;
                    s += S0[o2] + m1 * S1[o2] + m2 * S2[o2];
                }
            }
        }
    }
    BT[t] = s;
}

// ---- main composed conv: 256-thr block = 4 waves = 4 planes (wave-private LDS).
// Lane map: qr2=lane&15 (row pair), qc=lane>>4 (8-col group) -> b64 reads 2-way max.
// Staging: srow=lane&31, sth=lane>>5 -> b32 writes 2-way max. Stride 66 dwords.
#define HSD 66
__global__ __launch_bounds__(256) void convc_kernel(const unsigned short* __restrict__ Af16,
                                                    const unsigned* __restrict__ Wpk,
                                                    const float* __restrict__ BT,
                                                    float* __restrict__ xc) {
    __shared__ unsigned halo[4][36 * HSD];  // 38,016 B
    int tid = threadIdx.x;
    int w = tid >> 6, lane = tid & 63;
    int P = blockIdx.x * 4 + w;
    int b = blockIdx.y;
    int r1 = P >> 5, c1 = P & 31;
    int r1c = (r1 == 0) ? 0 : (r1 == 31) ? 2 : 1;
    int c1c = (c1 == 0) ? 0 : (c1 == 31) ? 2 : 1;

    const uint4* wsrc = (const uint4*)(Wpk + (size_t)((r1c * 3 + c1c) * 9 + 4) * 400);
    float bias = BT[r1 * 27 + c1c * 9 + 4];

    unsigned* myh = halo[w];
    for (int i = lane; i < 36 * HSD; i += 64) myh[i] = 0;

    int qr2 = lane & 15, qc = lane >> 4;
    int srow = lane & 31, sth = lane >> 5;
    int wbase = (srow + 2) * HSD + 8 * sth + 1;
    int idx4 = srow * 4 + sth * 2;

    const uint4* Ab4 = (const uint4*)(Af16 + (size_t)b * HW * HW);

    float acc0[8] = {}, acc1[8] = {};

    int pr0 = min(max(r1 - 2, 0), 31), pc0 = min(max(c1 - 2, 0), 31);
    uint4 pfA = Ab4[(size_t)(pr0 * 32 + pc0) * 128 + idx4];
    uint4 pfB = Ab4[(size_t)(pr0 * 32 + pc0) * 128 + idx4 + 1];

#pragma unroll 1
    for (int tp = 0; tp < 25; ++tp) {
        int tr = tp / 5, tc = tp - tr * 5;
        int apr = r1 + tr - 2, apc = c1 + tc - 2;
        bool valid = ((unsigned)apr < 32u) && ((unsigned)apc < 32u);  // wave-uniform
        uint4 curA = pfA, curB = pfB;
        if (tp < 24) {
            int t2 = tp + 1;
            int tr2 = t2 / 5, tc2 = t2 - tr2 * 5;
            int npr = min(max(r1 + tr2 - 2, 0), 31);
            int npc = min(max(c1 + tc2 - 2, 0), 31);
            pfA = Ab4[(size_t)(npr * 32 + npc) * 128 + idx4];
            pfB = Ab4[(size_t)(npr * 32 + npc) * 128 + idx4 + 1];
        }

        uint4 w4a = wsrc[tp * 4 + 0];  // uniform -> s_load
        uint4 w4b = wsrc[tp * 4 + 1];
        uint4 w4c = wsrc[tp * 4 + 2];
        uint4 w4d = wsrc[tp * 4 + 3];

        __syncthreads();  // unconditional: barrier counts match across waves
        if (valid) {
            unsigned* hb = &myh[wbase];
            hb[0] = curA.x; hb[1] = curA.y; hb[2] = curA.z; hb[3] = curA.w;
            hb[4] = curB.x; hb[5] = curB.y; hb[6] = curB.z; hb[7] = curB.w;
        }
        __syncthreads();
        if (!valid) continue;

        unsigned wr[16] = {w4a.x, w4a.y, w4a.z, w4a.w, w4b.x, w4b.y, w4b.z, w4b.w,
                           w4c.x, w4c.y, w4c.z, w4c.w, w4d.x, w4d.y, w4d.z, w4d.w};
        const unsigned* base = &myh[(2 * qr2) * HSD + 4 * qc];
#pragma unroll
        for (int i = 0; i < 6; ++i) {
            const unsigned* rp = base + i * HSD;
            uint2 e0 = *(const uint2*)rp;
            uint2 e1 = *(const uint2*)(rp + 2);
            uint2 e2 = *(const uint2*)(rp + 4);
            unsigned q0 = e0.x, q1 = e0.y, q2 = e1.x, q3 = e1.y, q4 = e2.x, q5 = e2.y;
            unsigned pp[12];
            pp[0] = q0;  pp[2] = q1;  pp[4] = q2;  pp[6] = q3;  pp[8] = q4;  pp[10] = q5;
            pp[1] = (q0 >> 16) | (q1 << 16);
            pp[3] = (q1 >> 16) | (q2 << 16);
            pp[5] = (q2 >> 16) | (q3 << 16);
            pp[7] = (q3 >> 16) | (q4 << 16);
            pp[9] = (q4 >> 16) | (q5 << 16);
            pp[11] = (q5 >> 16);
            if (i <= 4) {
                unsigned wa = wr[i * 3], wb_ = wr[i * 3 + 1], wc_ = wr[i * 3 + 2];
#pragma unroll
                for (int cc = 0; cc < 8; ++cc) {
                    float a = acc0[cc];
                    a = fdot2(wa, pp[cc], a);
                    a = fdot2(wb_, pp[cc + 2], a);
                    a = fdot2(wc_, pp[cc + 4], a);
                    acc0[cc] = a;
                }
            }
            if (i >= 1) {
                int u = i - 1;
                unsigned wa = wr[u * 3], wb_ = wr[u * 3 + 1], wc_ = wr[u * 3 + 2];
#pragma unroll
                for (int cc = 0; cc < 8; ++cc) {
                    float a = acc1[cc];
                    a = fdot2(wa, pp[cc], a);
                    a = fdot2(wb_, pp[cc + 2], a);
                    a = fdot2(wc_, pp[cc + 4], a);
                    acc1[cc] = a;
                }
            }
        }
    }

    float* xp = &xc[((size_t)b * HW + P) * HW];
    int o0 = (2 * qr2) * 32 + 8 * qc;
    int o1 = (2 * qr2 + 1) * 32 + 8 * qc;
    *(float4*)&xp[o0] = make_float4(acc0[0] + bias, acc0[1] + bias, acc0[2] + bias, acc0[3] + bias);
    *(float4*)&xp[o0 + 4] = make_float4(acc0[4] + bias, acc0[5] + bias, acc0[6] + bias, acc0[7] + bias);
    *(float4*)&xp[o1] = make_float4(acc1[0] + bias, acc1[1] + bias, acc1[2] + bias, acc1[3] + bias);
    *(float4*)&xp[o1 + 4] = make_float4(acc1[4] + bias, acc1[5] + bias, acc1[6] + bias, acc1[7] + bias);
}

// ---- expand: zero-padded copy Apad[b][plane][36][40] (f16)
__global__ __launch_bounds__(256) void expand_kernel(const unsigned short* __restrict__ Af16,
                                                     unsigned* __restrict__ Apad32) {
    int plane = blockIdx.x, b = blockIdx.y;
    const unsigned* src = (const unsigned*)(Af16 + ((size_t)b * HW + plane) * HW);
    unsigned* dst = Apad32 + ((size_t)b * HW + plane) * 720;
    for (int k = threadIdx.x; k < 720; k += 256) {
        int pr = k / 20, pcd = k - pr * 20;
        unsigned val = 0;
        if (pr >= 2 && pr < 34 && pcd >= 1 && pcd <= 16)
            val = src[(pr - 2) * 16 + (pcd - 1)];
        dst[k] = val;
    }
}

// ---- boundary fixup, barrier-free
__global__ __launch_bounds__(128) void fix_kernel(const unsigned* __restrict__ Apad32,
                                                  const unsigned* __restrict__ Wpk,
                                                  const float* __restrict__ BT,
                                                  float* __restrict__ xc) {
    __shared__ __align__(16) unsigned wl[3600];
    __shared__ float bts[9];
    int tid = threadIdx.x;
    int P = blockIdx.x, b = blockIdx.y;
    int r1 = P >> 5, c1 = P & 31;
    int r1c = (r1 == 0) ? 0 : (r1 == 31) ? 2 : 1;
    int c1c = (c1 == 0) ? 0 : (c1 == 31) ? 2 : 1;

    const unsigned* wsrc = Wpk + (size_t)(r1c * 3 + c1c) * 3600;
    for (int i = tid; i < 3600; i += 128) wl[i] = wsrc[i];
    if (tid < 9) bts[tid] = BT[r1 * 27 + c1c * 9 + tid];

    int li = tid;
    bool act = li < 124;
    int qr, qc;
    if (li < 32) { qr = 0; qc = li; }
    else if (li < 64) { qr = 31; qc = li - 32; }
    else if (li < 94) { qr = li - 63; qc = 0; }
    else { qr = min(li, 123) - 93; qc = 31; }
    int r2c = (qr == 0) ? 0 : (qr == 31) ? 2 : 1;
    int c2c = (qc == 0) ? 0 : (qc == 31) ? 2 : 1;
    int v = r2c * 3 + c2c;
    int sh = (qc & 1) * 16;
    int sd = qc >> 1;

    __syncthreads();
    float acc = 0.f;

#pragma unroll 1
    for (int tp = 0; tp < 25; ++tp) {
        int tr = tp / 5, tc = tp - tr * 5;
        int apr = r1 + tr - 2, apc = c1 + tc - 2;
        if ((unsigned)apr >= 32u || (unsigned)apc >= 32u) continue;
        const unsigned* tpl = Apad32 + ((size_t)b * HW + apr * 32 + apc) * 720;
        const uint4* wv4 = (const uint4*)&wl[v * 400 + tp * 16];
        uint4 wa = wv4[0], wb = wv4[1], wc2 = wv4[2], wd = wv4[3];
        unsigned wr[16] = {wa.x, wa.y, wa.z, wa.w, wb.x, wb.y, wb.z, wb.w,
                           wc2.x, wc2.y, wc2.z, wc2.w, wd.x, wd.y, wd.z, wd.w};
#pragma unroll
        for (int u = 0; u < 5; ++u) {
            const unsigned* rp = tpl + (qr + u) * 20 + sd;
            unsigned d0 = rp[0], d1 = rp[1], d2 = rp[2];
            unsigned pa = __builtin_amdgcn_alignbit(d1, d0, sh);
            unsigned pb = __builtin_amdgcn_alignbit(d2, d1, sh);
            unsigned pc_ = __builtin_amdgcn_alignbit(0u, d2, sh);
            acc = fdot2(wr[u * 3 + 0], pa, acc);
            acc = fdot2(wr[u * 3 + 1], pb, acc);
            acc = fdot2(wr[u * 3 + 2], pc_, acc);
        }
    }

    if (act)
        xc[((size_t)b * HW + P) * HW + qr * 32 + qc] = acc + bts[v];
}

__device__ __forceinline__ void top3_push(float v, float& t0, float& t1, float& t2) {
    float n0 = fminf(t0, v);
    t0 = fmaxf(t0, v);
    float n1 = fminf(t1, n0);
    t1 = fmaxf(t1, n0);
    t2 = fmaxf(t2, n1);
}

__global__ __launch_bounds__(256) void topk1_kernel(const float* __restrict__ xc,
                                                    float* __restrict__ part) {
    int q = blockIdx.x * 256 + threadIdx.x;
    int pc = blockIdx.y, bi = blockIdx.z;
    float t0 = -1e30f, t1 = -1e30f, t2 = -1e30f;
    const float* xp = xc + (size_t)bi * HW * HW;
    for (int p = pc * 32; p < pc * 32 + 32; ++p)
        top3_push(xp[(size_t)p * HW + q], t0, t1, t2);
    float* pp = part + (size_t)(bi * 32 + pc) * 3 * HW;
    pp[q] = t0;
    pp[HW + q] = t1;
    pp[2 * HW + q] = t2;
}

__global__ __launch_bounds__(256) void topk2_kernel(const float* __restrict__ part,
                                                    float* __restrict__ out) {
    int q = blockIdx.x * 256 + threadIdx.x;
    int bi = blockIdx.y;
    float t0 = -1e30f, t1 = -1e30f, t2 = -1e30f;
    const float* pp = part + (size_t)bi * 96 * HW;
    for (int k = 0; k < 96; ++k) top3_push(pp[(size_t)k * HW + q], t0, t1, t2);
    float* ob = out + (size_t)bi * 3 * HW;
    ob[q] = t0;
    ob[HW + q] = t1;
    ob[2 * HW + q] = t2;
}

extern "C" void kernel_launch(void* const* d_in, const int* in_sizes, int n_in,
                              void* d_out, int out_size, void* d_ws, size_t ws_size,
                              hipStream_t stream) {
    const float* x = (const float*)d_in[0];
    const float* w1 = (const float*)d_in[1];
    const float* b1 = (const float*)d_in[2];
    const float* w2 = (const float*)d_in[3];
    const float* b2 = (const float*)d_in[4];
    float* out = (float*)d_out;
    float* ws = (float*)d_ws;

    unsigned short* xnT = (unsigned short*)ws;
    unsigned short* Af16 = (unsigned short*)(ws + 524288);
    float* xc = ws + 2621440;
    unsigned* Wpk = (unsigned*)(ws + 6815744);
    float* BT = ws + 6848512;
    float* part = ws + 6849536;
    unsigned* Apad32 = (unsigned*)(ws + 7242752);
    float* G = ws + 10191872;

    norm_kernel<<<dim3(64, 4), 256, 0, stream>>>(x, xnT);
    aff_kernel<<<dim3(16, 16, 4), 256, 0, stream>>>(xnT, Af16);
    expand_kernel<<<dim3(1024, 4), 256, 0, stream>>>(Af16, Apad32);
    g_kernel<<<26, 256, 0, stream>>>(w1, w2, G);
    wcomp_kernel<<<81, 128, 0, stream>>>(G, Wpk);
    bt_kernel<<<1, 1024, 0, stream>>>(w2, b1, b2, BT);
    convc_kernel<<<dim3(256, 4), 256, 0, stream>>>(Af16, Wpk, BT, xc);
    fix_kernel<<<dim3(1024, 4), 128, 0, stream>>>(Apad32, Wpk, BT, xc);
    topk1_kernel<<<dim3(4, 32, 4), 256, 0, stream>>>(xc, part);
    topk2_kernel<<<dim3(4, 4), 256, 0, stream>>>(part, out);
}